// Round 3
// baseline (553.947 us; speedup 1.0000x reference)
//
#include <hip/hip_runtime.h>
#include <math.h>

// Problem constants
#define NN      50000
#define EE      800000
#define DIN     256
#define HF      128
#define RR      8
#define NHEADS  8
#define DHH     16
#define OUTC    3
#define M2      (NN * RR)                 // 400000 (t,rel) buckets
#define NB2     ((M2 + 255) / 256)        // 1563 scan blocks
#define CH2     ((NB2 + 255) / 256)       // 7 per-thread chunks in scan2

static inline int cdiv(long long a, int b) { return (int)((a + b - 1) / b); }

typedef __attribute__((ext_vector_type(8))) short short8;
typedef __attribute__((ext_vector_type(4))) float f32x4;

__device__ inline float bf2f(unsigned short u) {
    return __uint_as_float(((unsigned)u) << 16);
}
__device__ inline unsigned short f2bf(float f) {
    unsigned u = __float_as_uint(f);
    u += 0x7fffu + ((u >> 16) & 1u);   // RNE
    return (unsigned short)(u >> 16);
}

// ================= fused weight prep: transpose + hi/lo split, one dispatch =================
// regions (flat idx): Wp[0,32768) | W1[32768,163840) | root1[163840,180224)
//                     | W2[180224,311296) | root2[311296,327680) | Wg[327680,344064)
__global__ __launch_bounds__(256) void prep_weights(const float* __restrict__ Wp,
                                                    const float* __restrict__ W1,
                                                    const float* __restrict__ root1,
                                                    const float* __restrict__ W2,
                                                    const float* __restrict__ root2,
                                                    const float* __restrict__ Wg,
                                                    unsigned short* __restrict__ Wtp_hi,
                                                    unsigned short* __restrict__ Wtp_lo,
                                                    unsigned short* __restrict__ Wt1_hi,
                                                    unsigned short* __restrict__ Wt1_lo,
                                                    unsigned short* __restrict__ Wt2_hi,
                                                    unsigned short* __restrict__ Wt2_lo,
                                                    unsigned short* __restrict__ Wtg_hi,
                                                    unsigned short* __restrict__ Wtg_lo) {
    int i = blockIdx.x * 256 + threadIdx.x;
    if (i >= 344064) return;
    const float* src; unsigned short *dh, *dl; int k0, ldk, base;
    if (i < 32768)       { src = Wp;    dh = Wtp_hi; dl = Wtp_lo; k0 = 0;    ldk = 256;  base = 0; }
    else if (i < 163840) { src = W1;    dh = Wt1_hi; dl = Wt1_lo; k0 = 0;    ldk = 1152; base = 32768; }
    else if (i < 180224) { src = root1; dh = Wt1_hi; dl = Wt1_lo; k0 = 1024; ldk = 1152; base = 163840; }
    else if (i < 311296) { src = W2;    dh = Wt2_hi; dl = Wt2_lo; k0 = 0;    ldk = 1152; base = 180224; }
    else if (i < 327680) { src = root2; dh = Wt2_hi; dl = Wt2_lo; k0 = 1024; ldk = 1152; base = 311296; }
    else                 { src = Wg;    dh = Wtg_hi; dl = Wtg_lo; k0 = 0;    ldk = 128;  base = 327680; }
    int j = i - base;
    int k = j >> 7, n = j & 127;
    float f = src[(size_t)k * 128 + n];
    unsigned short hi = f2bf(f);
    unsigned short lo = f2bf(f - bf2f(hi));
    dh[(size_t)n * ldk + k0 + k] = hi;
    dl[(size_t)n * ldk + k0 + k] = lo;
}

// ================= CSR build, sorted by (tgt, rel) =================
__global__ __launch_bounds__(256) void count2_kernel(const int* __restrict__ tgt,
                                                     const int* __restrict__ et,
                                                     int* __restrict__ cnt2) {
    int i = blockIdx.x * 256 + threadIdx.x;
    if (i < EE) atomicAdd(&cnt2[tgt[i] * RR + et[i]], 1);
}

__global__ __launch_bounds__(256) void scan1_kernel(const int* __restrict__ cnt,
                                                    int* __restrict__ bsum, int n) {
    __shared__ int s[256];
    int t = threadIdx.x;
    int i = blockIdx.x * 256 + t;
    s[t] = (i < n) ? cnt[i] : 0;
    __syncthreads();
    for (int off = 128; off > 0; off >>= 1) {
        if (t < off) s[t] += s[t + off];
        __syncthreads();
    }
    if (t == 0) bsum[blockIdx.x] = s[0];
}

__global__ __launch_bounds__(256) void scan2_kernel(const int* __restrict__ bsum,
                                                    int* __restrict__ bbase,
                                                    int* __restrict__ tail,
                                                    int nb, int ch) {
    __shared__ int s[256];
    int t = threadIdx.x;
    int beg = t * ch;
    int end = beg + ch; if (end > nb) end = nb;
    int sum = 0;
    for (int i = beg; i < end; i++) sum += bsum[i];
    s[t] = sum;
    __syncthreads();
    for (int off = 1; off < 256; off <<= 1) {
        int u = (t >= off) ? s[t - off] : 0;
        __syncthreads();
        s[t] += u;
        __syncthreads();
    }
    int run = s[t] - sum;
    for (int i = beg; i < end; i++) {
        bbase[i] = run;
        run += bsum[i];
    }
    if (t == 255) *tail = s[255];
}

__global__ __launch_bounds__(256) void scan3_kernel(const int* __restrict__ cnt,
                                                    const int* __restrict__ bbase,
                                                    int* __restrict__ rowptr,
                                                    int* __restrict__ cursor, int n) {
    __shared__ int s[256];
    int t = threadIdx.x;
    int i = blockIdx.x * 256 + t;
    int v = (i < n) ? cnt[i] : 0;
    s[t] = v;
    __syncthreads();
    for (int off = 1; off < 256; off <<= 1) {
        int u = (t >= off) ? s[t - off] : 0;
        __syncthreads();
        s[t] += u;
        __syncthreads();
    }
    if (i < n) {
        int e = bbase[blockIdx.x] + s[t] - v;
        rowptr[i] = e;
        cursor[i] = e;
    }
}

__global__ __launch_bounds__(256) void fill2_kernel(const int* __restrict__ src,
                                                    const int* __restrict__ tgt,
                                                    const int* __restrict__ et,
                                                    int* __restrict__ cursor2,
                                                    int* __restrict__ csr_src2) {
    int e = blockIdx.x * 256 + threadIdx.x;
    if (e >= EE) return;
    int pos = atomicAdd(&cursor2[tgt[e] * RR + et[e]], 1);
    csr_src2[pos] = src[e];
}

// ================= generic MFMA GEMM (projection): 64-row tile, wave = 64r x 32c =================
// grid = cdiv(M,64); 4 waves; wave w owns cols [32w, 32w+32). acc[4][2] (4 row-groups x 2 col-blocks).
#define BK 32
#define APAD 36

template <bool SPLITA, bool ACC, bool BIAS, bool RELU, bool BF16OUT>
__global__ __launch_bounds__(256) void gemm_mfma(const void* __restrict__ Av, int lda,
                                                 const unsigned short* __restrict__ Bthi,
                                                 const unsigned short* __restrict__ Btlo, int ldk,
                                                 float* __restrict__ C,
                                                 unsigned short* __restrict__ Cb,
                                                 const float* __restrict__ bias,
                                                 int M, int K) {
    __shared__ unsigned short Ah[64 * APAD];
    __shared__ unsigned short Al[(SPLITA ? 64 : 1) * APAD];
    __shared__ unsigned short Bh[128 * APAD];
    __shared__ unsigned short Bl[128 * APAD];
    const int tid  = threadIdx.x;
    const int m0   = blockIdx.x * 64;
    const int w    = tid >> 6;
    const int lane = tid & 63;
    const int lrow = lane & 15;
    const int q    = lane >> 4;

    f32x4 acc[4][2];
#pragma unroll
    for (int t = 0; t < 4; t++)
#pragma unroll
        for (int c = 0; c < 2; c++) acc[t][c] = (f32x4){0.f, 0.f, 0.f, 0.f};

    const int srowA  = tid >> 2;          // 0..63
    const int spartA = (tid & 3) * 8;     // 0/8/16/24
    const int srowB  = tid >> 1;          // 0..127
    const int spartB = (tid & 1) * 16;    // 0/16

    for (int k0 = 0; k0 < K; k0 += BK) {
        if (SPLITA) {
            const float* A = (const float*)Av;
            int gm = m0 + srowA;
            float va[8];
            if (gm < M) {
                const float* ap = &A[(size_t)gm * lda + k0 + spartA];
                float4 v0 = *reinterpret_cast<const float4*>(ap);
                float4 v1 = *reinterpret_cast<const float4*>(ap + 4);
                va[0] = v0.x; va[1] = v0.y; va[2] = v0.z; va[3] = v0.w;
                va[4] = v1.x; va[5] = v1.y; va[6] = v1.z; va[7] = v1.w;
            } else {
#pragma unroll
                for (int j = 0; j < 8; j++) va[j] = 0.f;
            }
            unsigned hw[4], lw[4];
#pragma unroll
            for (int j = 0; j < 4; j++) {
                unsigned short h0 = f2bf(va[2 * j]);
                unsigned short h1 = f2bf(va[2 * j + 1]);
                unsigned short l0 = f2bf(va[2 * j] - bf2f(h0));
                unsigned short l1 = f2bf(va[2 * j + 1] - bf2f(h1));
                hw[j] = (unsigned)h0 | ((unsigned)h1 << 16);
                lw[j] = (unsigned)l0 | ((unsigned)l1 << 16);
            }
            *reinterpret_cast<uint4*>(&Ah[srowA * APAD + spartA]) = make_uint4(hw[0], hw[1], hw[2], hw[3]);
            *reinterpret_cast<uint4*>(&Al[srowA * APAD + spartA]) = make_uint4(lw[0], lw[1], lw[2], lw[3]);
        } else {
            const unsigned short* A = (const unsigned short*)Av;
            int gm = m0 + srowA;
            uint4 v = make_uint4(0u, 0u, 0u, 0u);
            if (gm < M) v = *reinterpret_cast<const uint4*>(&A[(size_t)gm * lda + k0 + spartA]);
            *reinterpret_cast<uint4*>(&Ah[srowA * APAD + spartA]) = v;
        }
        {
            const unsigned short* bh = &Bthi[(size_t)srowB * ldk + k0 + spartB];
            const unsigned short* bl = &Btlo[(size_t)srowB * ldk + k0 + spartB];
            *reinterpret_cast<uint4*>(&Bh[srowB * APAD + spartB])     = *reinterpret_cast<const uint4*>(bh);
            *reinterpret_cast<uint4*>(&Bh[srowB * APAD + spartB + 8]) = *reinterpret_cast<const uint4*>(bh + 8);
            *reinterpret_cast<uint4*>(&Bl[srowB * APAD + spartB])     = *reinterpret_cast<const uint4*>(bl);
            *reinterpret_cast<uint4*>(&Bl[srowB * APAD + spartB + 8]) = *reinterpret_cast<const uint4*>(bl + 8);
        }
        __syncthreads();

        short8 ah[4], al[4];
#pragma unroll
        for (int t = 0; t < 4; t++) {
            ah[t] = *reinterpret_cast<const short8*>(&Ah[(t * 16 + lrow) * APAD + q * 8]);
            if (SPLITA)
                al[t] = *reinterpret_cast<const short8*>(&Al[(t * 16 + lrow) * APAD + q * 8]);
        }
#pragma unroll
        for (int cc = 0; cc < 2; cc++) {
            int cb = w * 2 + cc;
            short8 bh = *reinterpret_cast<const short8*>(&Bh[(cb * 16 + lrow) * APAD + q * 8]);
            short8 bl = *reinterpret_cast<const short8*>(&Bl[(cb * 16 + lrow) * APAD + q * 8]);
#pragma unroll
            for (int t = 0; t < 4; t++) {
                acc[t][cc] = __builtin_amdgcn_mfma_f32_16x16x32_bf16(ah[t], bl, acc[t][cc], 0, 0, 0);
                if (SPLITA)
                    acc[t][cc] = __builtin_amdgcn_mfma_f32_16x16x32_bf16(al[t], bh, acc[t][cc], 0, 0, 0);
                acc[t][cc] = __builtin_amdgcn_mfma_f32_16x16x32_bf16(ah[t], bh, acc[t][cc], 0, 0, 0);
            }
        }
        __syncthreads();
    }

#pragma unroll
    for (int t = 0; t < 4; t++) {
#pragma unroll
        for (int r = 0; r < 4; r++) {
            int gm = m0 + t * 16 + q * 4 + r;
            if (gm >= M) continue;
#pragma unroll
            for (int cc = 0; cc < 2; cc++) {
                int gn = (w * 2 + cc) * 16 + lrow;
                float v = acc[t][cc][r];
                if (BIAS) v += bias[gn];
                if (ACC)  v += C[(size_t)gm * HF + gn];
                if (RELU) v = fmaxf(v, 0.f);
                C[(size_t)gm * HF + gn] = v;
                if (BF16OUT) Cb[(size_t)gm * HF + gn] = f2bf(v);
            }
        }
    }
}

// ================= merged RGCN layer GEMM: 64-row tile, wave = 64r x 32c =================
// hout = relu( aggb[N,1024] @ W[0:1024]^T + hin[N,128] @ root^T + bias ), + bf16 mirror.
__global__ __launch_bounds__(256) void gemm_rgcn(const unsigned short* __restrict__ aggb,
                                                 const float* __restrict__ hin,
                                                 const unsigned short* __restrict__ Bthi,
                                                 const unsigned short* __restrict__ Btlo,
                                                 float* __restrict__ hout,
                                                 unsigned short* __restrict__ hbout,
                                                 const float* __restrict__ bias, int M) {
    const int LDK = (RR + 1) * HF;  // 1152
    __shared__ unsigned short Ah[64 * APAD];
    __shared__ unsigned short Al[64 * APAD];
    __shared__ unsigned short Bh[128 * APAD];
    __shared__ unsigned short Bl[128 * APAD];
    const int tid  = threadIdx.x;
    const int m0   = blockIdx.x * 64;
    const int w    = tid >> 6;
    const int lane = tid & 63;
    const int lrow = lane & 15;
    const int q    = lane >> 4;

    f32x4 acc[4][2];
#pragma unroll
    for (int t = 0; t < 4; t++)
#pragma unroll
        for (int c = 0; c < 2; c++) acc[t][c] = (f32x4){0.f, 0.f, 0.f, 0.f};

    const int srowA  = tid >> 2;          // 0..63
    const int spartA = (tid & 3) * 8;     // 0/8/16/24
    const int srowB  = tid >> 1;          // 0..127
    const int spartB = (tid & 1) * 16;    // 0/16

    // ---- phase 1: K = 0..1024, A = aggb (bf16) ----
    for (int k0 = 0; k0 < RR * HF; k0 += BK) {
        {
            int gm = m0 + srowA;
            uint4 v = make_uint4(0u, 0u, 0u, 0u);
            if (gm < M) v = *reinterpret_cast<const uint4*>(&aggb[(size_t)gm * (RR * HF) + k0 + spartA]);
            *reinterpret_cast<uint4*>(&Ah[srowA * APAD + spartA]) = v;
        }
        {
            const unsigned short* bh = &Bthi[(size_t)srowB * LDK + k0 + spartB];
            const unsigned short* bl = &Btlo[(size_t)srowB * LDK + k0 + spartB];
            *reinterpret_cast<uint4*>(&Bh[srowB * APAD + spartB])     = *reinterpret_cast<const uint4*>(bh);
            *reinterpret_cast<uint4*>(&Bh[srowB * APAD + spartB + 8]) = *reinterpret_cast<const uint4*>(bh + 8);
            *reinterpret_cast<uint4*>(&Bl[srowB * APAD + spartB])     = *reinterpret_cast<const uint4*>(bl);
            *reinterpret_cast<uint4*>(&Bl[srowB * APAD + spartB + 8]) = *reinterpret_cast<const uint4*>(bl + 8);
        }
        __syncthreads();
        short8 ah[4];
#pragma unroll
        for (int t = 0; t < 4; t++)
            ah[t] = *reinterpret_cast<const short8*>(&Ah[(t * 16 + lrow) * APAD + q * 8]);
#pragma unroll
        for (int cc = 0; cc < 2; cc++) {
            int cb = w * 2 + cc;
            short8 bh = *reinterpret_cast<const short8*>(&Bh[(cb * 16 + lrow) * APAD + q * 8]);
            short8 bl = *reinterpret_cast<const short8*>(&Bl[(cb * 16 + lrow) * APAD + q * 8]);
#pragma unroll
            for (int t = 0; t < 4; t++) {
                acc[t][cc] = __builtin_amdgcn_mfma_f32_16x16x32_bf16(ah[t], bl, acc[t][cc], 0, 0, 0);
                acc[t][cc] = __builtin_amdgcn_mfma_f32_16x16x32_bf16(ah[t], bh, acc[t][cc], 0, 0, 0);
            }
        }
        __syncthreads();
    }

    // ---- phase 2: K = 1024..1152, A = hin (fp32 split) ----
    for (int k0 = 0; k0 < HF; k0 += BK) {
        {
            int gm = m0 + srowA;
            float va[8];
            if (gm < M) {
                const float* ap = &hin[(size_t)gm * HF + k0 + spartA];
                float4 v0 = *reinterpret_cast<const float4*>(ap);
                float4 v1 = *reinterpret_cast<const float4*>(ap + 4);
                va[0] = v0.x; va[1] = v0.y; va[2] = v0.z; va[3] = v0.w;
                va[4] = v1.x; va[5] = v1.y; va[6] = v1.z; va[7] = v1.w;
            } else {
#pragma unroll
                for (int j = 0; j < 8; j++) va[j] = 0.f;
            }
            unsigned hw[4], lw[4];
#pragma unroll
            for (int j = 0; j < 4; j++) {
                unsigned short h0 = f2bf(va[2 * j]);
                unsigned short h1 = f2bf(va[2 * j + 1]);
                unsigned short l0 = f2bf(va[2 * j] - bf2f(h0));
                unsigned short l1 = f2bf(va[2 * j + 1] - bf2f(h1));
                hw[j] = (unsigned)h0 | ((unsigned)h1 << 16);
                lw[j] = (unsigned)l0 | ((unsigned)l1 << 16);
            }
            *reinterpret_cast<uint4*>(&Ah[srowA * APAD + spartA]) = make_uint4(hw[0], hw[1], hw[2], hw[3]);
            *reinterpret_cast<uint4*>(&Al[srowA * APAD + spartA]) = make_uint4(lw[0], lw[1], lw[2], lw[3]);
        }
        {
            const unsigned short* bh = &Bthi[(size_t)srowB * LDK + RR * HF + k0 + spartB];
            const unsigned short* bl = &Btlo[(size_t)srowB * LDK + RR * HF + k0 + spartB];
            *reinterpret_cast<uint4*>(&Bh[srowB * APAD + spartB])     = *reinterpret_cast<const uint4*>(bh);
            *reinterpret_cast<uint4*>(&Bh[srowB * APAD + spartB + 8]) = *reinterpret_cast<const uint4*>(bh + 8);
            *reinterpret_cast<uint4*>(&Bl[srowB * APAD + spartB])     = *reinterpret_cast<const uint4*>(bl);
            *reinterpret_cast<uint4*>(&Bl[srowB * APAD + spartB + 8]) = *reinterpret_cast<const uint4*>(bl + 8);
        }
        __syncthreads();
        short8 ah[4], al[4];
#pragma unroll
        for (int t = 0; t < 4; t++) {
            ah[t] = *reinterpret_cast<const short8*>(&Ah[(t * 16 + lrow) * APAD + q * 8]);
            al[t] = *reinterpret_cast<const short8*>(&Al[(t * 16 + lrow) * APAD + q * 8]);
        }
#pragma unroll
        for (int cc = 0; cc < 2; cc++) {
            int cb = w * 2 + cc;
            short8 bh = *reinterpret_cast<const short8*>(&Bh[(cb * 16 + lrow) * APAD + q * 8]);
            short8 bl = *reinterpret_cast<const short8*>(&Bl[(cb * 16 + lrow) * APAD + q * 8]);
#pragma unroll
            for (int t = 0; t < 4; t++) {
                acc[t][cc] = __builtin_amdgcn_mfma_f32_16x16x32_bf16(ah[t], bl, acc[t][cc], 0, 0, 0);
                acc[t][cc] = __builtin_amdgcn_mfma_f32_16x16x32_bf16(al[t], bh, acc[t][cc], 0, 0, 0);
                acc[t][cc] = __builtin_amdgcn_mfma_f32_16x16x32_bf16(ah[t], bh, acc[t][cc], 0, 0, 0);
            }
        }
        __syncthreads();
    }

#pragma unroll
    for (int t = 0; t < 4; t++) {
#pragma unroll
        for (int r = 0; r < 4; r++) {
            int gm = m0 + t * 16 + q * 4 + r;
            if (gm >= M) continue;
#pragma unroll
            for (int cc = 0; cc < 2; cc++) {
                int gn = (w * 2 + cc) * 16 + lrow;
                float v = fmaxf(acc[t][cc][r] + bias[gn], 0.f);
                hout[(size_t)gm * HF + gn] = v;
                hbout[(size_t)gm * HF + gn] = f2bf(v);
            }
        }
    }
}

// ================= z GEMM with fused attention scores =================
__global__ __launch_bounds__(256) void gemm_z(const float* __restrict__ hin,
                                              const unsigned short* __restrict__ Bthi,
                                              const unsigned short* __restrict__ Btlo,
                                              const float* __restrict__ att,
                                              unsigned short* __restrict__ zb,
                                              float* __restrict__ a_src,
                                              float* __restrict__ a_tgt, int M) {
    __shared__ unsigned short Ah[128 * APAD];
    __shared__ unsigned short Al[128 * APAD];
    __shared__ unsigned short Bh[128 * APAD];
    __shared__ unsigned short Bl[128 * APAD];
    const int tid  = threadIdx.x;
    const int m0   = blockIdx.x * 128;
    const int w    = tid >> 6;
    const int lane = tid & 63;
    const int lrow = lane & 15;
    const int q    = lane >> 4;

    f32x4 acc[2][8];
#pragma unroll
    for (int t = 0; t < 2; t++)
#pragma unroll
        for (int c = 0; c < 8; c++) acc[t][c] = (f32x4){0.f, 0.f, 0.f, 0.f};

    const int srow  = tid >> 1;
    const int spart = (tid & 1) * 16;

    for (int k0 = 0; k0 < HF; k0 += BK) {
        {
            int gm = m0 + srow;
            float va[16];
            if (gm < M) {
                const float* ap = &hin[(size_t)gm * HF + k0 + spart];
#pragma unroll
                for (int j = 0; j < 4; j++) {
                    float4 v = *reinterpret_cast<const float4*>(ap + j * 4);
                    va[j * 4 + 0] = v.x; va[j * 4 + 1] = v.y; va[j * 4 + 2] = v.z; va[j * 4 + 3] = v.w;
                }
            } else {
#pragma unroll
                for (int j = 0; j < 16; j++) va[j] = 0.f;
            }
            unsigned hw[8], lw[8];
#pragma unroll
            for (int j = 0; j < 8; j++) {
                unsigned short h0 = f2bf(va[2 * j]);
                unsigned short h1 = f2bf(va[2 * j + 1]);
                unsigned short l0 = f2bf(va[2 * j] - bf2f(h0));
                unsigned short l1 = f2bf(va[2 * j + 1] - bf2f(h1));
                hw[j] = (unsigned)h0 | ((unsigned)h1 << 16);
                lw[j] = (unsigned)l0 | ((unsigned)l1 << 16);
            }
            *reinterpret_cast<uint4*>(&Ah[srow * APAD + spart])     = make_uint4(hw[0], hw[1], hw[2], hw[3]);
            *reinterpret_cast<uint4*>(&Ah[srow * APAD + spart + 8]) = make_uint4(hw[4], hw[5], hw[6], hw[7]);
            *reinterpret_cast<uint4*>(&Al[srow * APAD + spart])     = make_uint4(lw[0], lw[1], lw[2], lw[3]);
            *reinterpret_cast<uint4*>(&Al[srow * APAD + spart + 8]) = make_uint4(lw[4], lw[5], lw[6], lw[7]);
        }
        {
            const unsigned short* bh = &Bthi[(size_t)srow * HF + k0 + spart];
            const unsigned short* bl = &Btlo[(size_t)srow * HF + k0 + spart];
            *reinterpret_cast<uint4*>(&Bh[srow * APAD + spart])     = *reinterpret_cast<const uint4*>(bh);
            *reinterpret_cast<uint4*>(&Bh[srow * APAD + spart + 8]) = *reinterpret_cast<const uint4*>(bh + 8);
            *reinterpret_cast<uint4*>(&Bl[srow * APAD + spart])     = *reinterpret_cast<const uint4*>(bl);
            *reinterpret_cast<uint4*>(&Bl[srow * APAD + spart + 8]) = *reinterpret_cast<const uint4*>(bl + 8);
        }
        __syncthreads();
        short8 ah[2], al[2];
#pragma unroll
        for (int t = 0; t < 2; t++) {
            ah[t] = *reinterpret_cast<const short8*>(&Ah[(w * 32 + t * 16 + lrow) * APAD + q * 8]);
            al[t] = *reinterpret_cast<const short8*>(&Al[(w * 32 + t * 16 + lrow) * APAD + q * 8]);
        }
#pragma unroll
        for (int c = 0; c < 8; c++) {
            short8 bh = *reinterpret_cast<const short8*>(&Bh[(c * 16 + lrow) * APAD + q * 8]);
            short8 bl = *reinterpret_cast<const short8*>(&Bl[(c * 16 + lrow) * APAD + q * 8]);
#pragma unroll
            for (int t = 0; t < 2; t++) {
                acc[t][c] = __builtin_amdgcn_mfma_f32_16x16x32_bf16(ah[t], bl, acc[t][c], 0, 0, 0);
                acc[t][c] = __builtin_amdgcn_mfma_f32_16x16x32_bf16(al[t], bh, acc[t][c], 0, 0, 0);
                acc[t][c] = __builtin_amdgcn_mfma_f32_16x16x32_bf16(ah[t], bh, acc[t][c], 0, 0, 0);
            }
        }
        __syncthreads();
    }

    float att_s[8], att_t[8];
#pragma unroll
    for (int c = 0; c < 8; c++) {
        att_s[c] = att[c * 32 + lrow];
        att_t[c] = att[c * 32 + 16 + lrow];
    }

#pragma unroll
    for (int t = 0; t < 2; t++) {
#pragma unroll
        for (int r = 0; r < 4; r++) {
            int gm = m0 + w * 32 + t * 16 + q * 4 + r;
            if (gm >= M) continue;
#pragma unroll
            for (int c = 0; c < 8; c++) {
                int gn = c * 16 + lrow;
                float v = acc[t][c][r];
                zb[(size_t)gm * HF + gn] = f2bf(v);
                float ps = v * att_s[c];
                float pt = v * att_t[c];
#pragma unroll
                for (int off = 1; off < 16; off <<= 1) {
                    ps += __shfl_xor(ps, off);
                    pt += __shfl_xor(pt, off);
                }
                if (lrow == 0) {
                    a_src[(size_t)gm * NHEADS + c] = ps;
                    a_tgt[(size_t)gm * NHEADS + c] = pt;
                }
            }
        }
    }
}

// ================= RGCN gather: all 8 relations concurrent per wave =================
// lane = (rel = lane>>3, colgroup = lane&7); each 8-lane group owns one relation's
// segment and accumulates 16 columns per lane in registers. No shuffles, no halves.
__device__ inline void acc8(float* a, uint4 v) {
    a[0] += bf2f((unsigned short)(v.x & 0xffffu));
    a[1] += bf2f((unsigned short)(v.x >> 16));
    a[2] += bf2f((unsigned short)(v.y & 0xffffu));
    a[3] += bf2f((unsigned short)(v.y >> 16));
    a[4] += bf2f((unsigned short)(v.z & 0xffffu));
    a[5] += bf2f((unsigned short)(v.z >> 16));
    a[6] += bf2f((unsigned short)(v.w & 0xffffu));
    a[7] += bf2f((unsigned short)(v.w >> 16));
}

__global__ __launch_bounds__(256) void rgcn_agg_sorted(const unsigned short* __restrict__ hb,
                                                       const int* __restrict__ rowptr2,
                                                       const int* __restrict__ csr_src2,
                                                       unsigned short* __restrict__ agg) {
    int w = (blockIdx.x * 256 + threadIdx.x) >> 6;
    if (w >= NN) return;
    int lane = threadIdx.x & 63;
    int r    = lane >> 3;          // relation handled by this lane's group
    int cg   = (lane & 7) * 16;    // 16 columns (32 B) of the 128-wide row
    int b8   = w * RR;

    // segment bounds for this lane's relation: lanes 0..8 load the 9 rowptrs,
    // then broadcast (no per-segment rowptr loads in the hot path)
    int rp  = rowptr2[b8 + (lane < 9 ? lane : 8)];
    int beg = __shfl(rp, r);
    int end = __shfl(rp, r + 1);

    float a[16];
#pragma unroll
    for (int j = 0; j < 16; j++) a[j] = 0.f;

    // 2-way unrolled edge loop: 2 edges (4x 16B loads) in flight per group,
    // all 8 relations' chains run concurrently across the wave
    int e = beg;
    for (; e + 1 < end; e += 2) {
        int s0 = csr_src2[e];
        int s1 = csr_src2[e + 1];
        const uint4* p0 = reinterpret_cast<const uint4*>(&hb[(size_t)s0 * HF + cg]);
        const uint4* p1 = reinterpret_cast<const uint4*>(&hb[(size_t)s1 * HF + cg]);
        uint4 v00 = p0[0];
        uint4 v01 = p0[1];
        uint4 v10 = p1[0];
        uint4 v11 = p1[1];
        acc8(a,     v00);
        acc8(a + 8, v01);
        acc8(a,     v10);
        acc8(a + 8, v11);
    }
    if (e < end) {
        int s0 = csr_src2[e];
        const uint4* p0 = reinterpret_cast<const uint4*>(&hb[(size_t)s0 * HF + cg]);
        uint4 v00 = p0[0];
        uint4 v01 = p0[1];
        acc8(a,     v00);
        acc8(a + 8, v01);
    }

    int n = end - beg;
    float inv = 1.f / (float)(n > 1 ? n : 1);
    unsigned ow[8];
#pragma unroll
    for (int j = 0; j < 8; j++) {
        ow[j] = (unsigned)f2bf(a[2 * j] * inv) | ((unsigned)f2bf(a[2 * j + 1] * inv) << 16);
    }
    // lane offset = r*128 + (lane&7)*16 = lane*16 -> fully contiguous 2KB store per node
    unsigned short* o = &agg[(size_t)w * (RR * HF) + r * HF + cg];
    *reinterpret_cast<uint4*>(o)     = make_uint4(ow[0], ow[1], ow[2], ow[3]);
    *reinterpret_cast<uint4*>(o + 8) = make_uint4(ow[4], ow[5], ow[6], ow[7]);
}

// ================= GAT: two-pass, chunked-shuffle weights + half-split accumulate =================
// Pass A: segment max in (e8 = lane>>3, hdA = lane&7) layout.
// Pass B: chunks of 8 edges. Weight step computes 8 edges x 8 heads of exp-weights in
// one instruction stream (pass-A layout); consume step splits the wave into 2 halves,
// each half handles one edge per j-iteration with 4 cols/lane (uint2 loads), pulling
// (w, src) via __shfl. Invalid tail edges carry w=0, s=0 (reads zb row 0, adds 0).
__global__ __launch_bounds__(256) void gat_kernel(const int* __restrict__ rowptr2,
                                                  const int* __restrict__ csr_src2,
                                                  const float* __restrict__ a_src,
                                                  const float* __restrict__ a_tgt,
                                                  const unsigned short* __restrict__ zb,
                                                  const float* __restrict__ bg,
                                                  const float* __restrict__ Wf,
                                                  const float* __restrict__ bf,
                                                  float* __restrict__ out) {
    int w = (blockIdx.x * 256 + threadIdx.x) >> 6;
    if (w >= NN) return;
    int lane = threadIdx.x & 63;
    int beg = rowptr2[w * RR], end = rowptr2[w * RR + RR];

    // ---- pass A: segment max, 8 edges x 8 heads in parallel ----
    int hdA = lane & 7;
    int e8  = lane >> 3;
    float atA = a_tgt[w * NHEADS + hdA];
    float m = -1e30f;
    for (int e = beg + e8; e < end; e += 8) {
        int s = csr_src2[e];
        float a = a_src[s * NHEADS + hdA] + atA;
        a = a > 0.f ? a : 0.2f * a;
        m = fmaxf(m, a);
    }
    m = fmaxf(m, __shfl_xor(m, 8));
    m = fmaxf(m, __shfl_xor(m, 16));
    m = fmaxf(m, __shfl_xor(m, 32));
    // every lane now holds the max for head hdA

    // ---- pass B: chunked weights + half-split accumulate ----
    int half = lane >> 5;          // which edge of the pair this half-wave handles
    int l32  = lane & 31;
    int hd   = l32 >> 2;           // head for consumption (4 lanes per head per half)
    int c0   = l32 * 4;            // 4 cols of the 128-wide z row

    float l = 0.f;
    float ax0 = 0.f, ax1 = 0.f, ax2 = 0.f, ax3 = 0.f;

    for (int e0 = beg; e0 < end; e0 += 8) {
        // weight step (pass-A layout): one exp instr covers 8 edges x 8 heads
        int eA = e0 + e8;
        float wA = 0.f;
        int   sA = 0;
        if (eA < end) {
            sA = csr_src2[eA];
            float a = a_src[sA * NHEADS + hdA] + atA;
            a = a > 0.f ? a : 0.2f * a;
            wA = __expf(a - m);
        }
        // consume step: 4 iterations x 2 edges (one per half-wave)
#pragma unroll
        for (int j = 0; j < 4; j++) {
            int idx  = (2 * j + half) * 8 + hd;
            float wv = __shfl(wA, idx);
            int   sv = __shfl(sA, idx);
            uint2 z = *reinterpret_cast<const uint2*>(&zb[(size_t)sv * HF + c0]);
            l   += wv;
            ax0 += bf2f((unsigned short)(z.x & 0xffffu)) * wv;
            ax1 += bf2f((unsigned short)(z.x >> 16)) * wv;
            ax2 += bf2f((unsigned short)(z.y & 0xffffu)) * wv;
            ax3 += bf2f((unsigned short)(z.y >> 16)) * wv;
        }
    }
    // combine the two halves (both halves end up with full sums)
    l   += __shfl_xor(l, 32);
    ax0 += __shfl_xor(ax0, 32);
    ax1 += __shfl_xor(ax1, 32);
    ax2 += __shfl_xor(ax2, 32);
    ax3 += __shfl_xor(ax3, 32);

    float inv = 1.f / fmaxf(l, 1e-16f);
    float v0 = ax0 * inv + bg[c0];
    float v1 = ax1 * inv + bg[c0 + 1];
    float v2 = ax2 * inv + bg[c0 + 2];
    float v3 = ax3 * inv + bg[c0 + 3];

    float p0 = v0 * Wf[c0 * 3 + 0] + v1 * Wf[(c0 + 1) * 3 + 0]
             + v2 * Wf[(c0 + 2) * 3 + 0] + v3 * Wf[(c0 + 3) * 3 + 0];
    float p1 = v0 * Wf[c0 * 3 + 1] + v1 * Wf[(c0 + 1) * 3 + 1]
             + v2 * Wf[(c0 + 2) * 3 + 1] + v3 * Wf[(c0 + 3) * 3 + 1];
    float p2 = v0 * Wf[c0 * 3 + 2] + v1 * Wf[(c0 + 1) * 3 + 2]
             + v2 * Wf[(c0 + 2) * 3 + 2] + v3 * Wf[(c0 + 3) * 3 + 2];
    // lanes 0..31 cover all 128 cols once; reduce within the half
#pragma unroll
    for (int off = 16; off > 0; off >>= 1) {
        p0 += __shfl_xor(p0, off);
        p1 += __shfl_xor(p1, off);
        p2 += __shfl_xor(p2, off);
    }
    if (lane == 0) {
        float l0v = p0 + bf[0], l1v = p1 + bf[1], l2v = p2 + bf[2];
        float mm = fmaxf(l0v, fmaxf(l1v, l2v));
        float lse = mm + logf(expf(l0v - mm) + expf(l1v - mm) + expf(l2v - mm));
        out[(size_t)w * 3 + 0] = l0v - lse;
        out[(size_t)w * 3 + 1] = l1v - lse;
        out[(size_t)w * 3 + 2] = l2v - lse;
    }
}

// ================= launch =================
extern "C" void kernel_launch(void* const* d_in, const int* in_sizes, int n_in,
                              void* d_out, int out_size, void* d_ws, size_t ws_size,
                              hipStream_t stream) {
    const float* x     = (const float*)d_in[0];
    const int*   ei    = (const int*)d_in[1];
    const int*   etype = (const int*)d_in[2];
    const float* Wp    = (const float*)d_in[3];
    const float* bp    = (const float*)d_in[4];
    const float* W1    = (const float*)d_in[5];
    const float* root1 = (const float*)d_in[6];
    const float* b1    = (const float*)d_in[7];
    const float* W2    = (const float*)d_in[8];
    const float* root2 = (const float*)d_in[9];
    const float* b2    = (const float*)d_in[10];
    const float* Wg    = (const float*)d_in[11];
    const float* att   = (const float*)d_in[12];
    const float* bg    = (const float*)d_in[13];
    const float* Wf    = (const float*)d_in[14];
    const float* bf    = (const float*)d_in[15];
    (void)in_sizes; (void)n_in; (void)out_size; (void)ws_size;

    const int* srcv = ei;
    const int* tgtv = ei + EE;

    // ---- workspace layout (bytes), ~185.4 MB ----
    char* base = (char*)d_ws;
    unsigned short* aggb = (unsigned short*)(base + 0);   // N*1024*2 = 102,400,000
    int* cnt2    = (int*)(base + 96000000);               // 1,600,000 (aliased, dead before walk 1)
    int* cursor2 = (int*)(base + 98000000);               // 1,600,000
    int* bsum2   = (int*)(base + 99700000);               // 6,256
    int* bbase2  = (int*)(base + 99800000);               // 6,256
    unsigned short* zb = (unsigned short*)(base + 0);     // 12,800,000 (GAT phase)
    float* a_src = (float*)(base + 12800000);             // 1,600,000
    float* a_tgt = (float*)(base + 14400000);             // 1,600,000
    float* h1    = (float*)(base + 102400000);            // 25,600,000
    float* h2    = (float*)(base + 128000000);            // 25,600,000
    unsigned short* h1b = (unsigned short*)(base + 153600000); // 12,800,000
    unsigned short* h2b = (unsigned short*)(base + 166400000); // 12,800,000
    int* csr_src2 = (int*)(base + 179200000);             // 3,200,000
    int* rowptr2  = (int*)(base + 182400000);             // 1,600,016
    unsigned short* Wtp_hi = (unsigned short*)(base + 184000016); // 65,536
    unsigned short* Wtp_lo = (unsigned short*)(base + 184065552); // 65,536
    unsigned short* Wt1_hi = (unsigned short*)(base + 184131088); // 294,912
    unsigned short* Wt1_lo = (unsigned short*)(base + 184426000); // 294,912
    unsigned short* Wt2_hi = (unsigned short*)(base + 184720912); // 294,912
    unsigned short* Wt2_lo = (unsigned short*)(base + 185015824); // 294,912
    unsigned short* Wtg_hi = (unsigned short*)(base + 185310736); // 32,768
    unsigned short* Wtg_lo = (unsigned short*)(base + 185343504); // 32,768

    // ---- weight prep: one dispatch ----
    prep_weights<<<cdiv(344064, 256), 256, 0, stream>>>(
        Wp, W1, root1, W2, root2, Wg,
        Wtp_hi, Wtp_lo, Wt1_hi, Wt1_lo, Wt2_hi, Wt2_lo, Wtg_hi, Wtg_lo);

    // ---- CSR build, sorted by (tgt, rel) ----
    hipMemsetAsync(cnt2, 0, (size_t)M2 * 4, stream);
    count2_kernel<<<cdiv(EE, 256), 256, 0, stream>>>(tgtv, etype, cnt2);
    scan1_kernel<<<NB2, 256, 0, stream>>>(cnt2, bsum2, M2);
    scan2_kernel<<<1, 256, 0, stream>>>(bsum2, bbase2, &rowptr2[M2], NB2, CH2);
    scan3_kernel<<<NB2, 256, 0, stream>>>(cnt2, bbase2, rowptr2, cursor2, M2);
    fill2_kernel<<<cdiv(EE, 256), 256, 0, stream>>>(srcv, tgtv, etype, cursor2, csr_src2);

    const int ggrid64 = cdiv(NN, 64);    // 782 (projection + rgcn GEMMs)
    const int ggrid   = cdiv(NN, 128);   // 391 (z GEMM)
    const int nwgrid  = cdiv(NN, 4);

    // ---- projection: h1 = x @ Wp + bp (fp32-effective) + h1b mirror ----
    gemm_mfma<true, false, true, false, true><<<ggrid64, 256, 0, stream>>>(
        x, DIN, Wtp_hi, Wtp_lo, DIN, h1, h1b, bp, NN, DIN);

    // ---- RGCN layer 1: h1 -> h2 ----
    rgcn_agg_sorted<<<nwgrid, 256, 0, stream>>>(h1b, rowptr2, csr_src2, aggb);
    gemm_rgcn<<<ggrid64, 256, 0, stream>>>(aggb, h1, Wt1_hi, Wt1_lo, h2, h2b, b1, NN);

    // ---- RGCN layer 2: h2 -> h1 ----
    rgcn_agg_sorted<<<nwgrid, 256, 0, stream>>>(h2b, rowptr2, csr_src2, aggb);
    gemm_rgcn<<<ggrid64, 256, 0, stream>>>(aggb, h2, Wt2_hi, Wt2_lo, h1, h1b, b2, NN);

    // ---- GAT: z GEMM (fused scores) + two-pass softmax-aggregate ----
    gemm_z<<<ggrid, 256, 0, stream>>>(h1, Wtg_hi, Wtg_lo, att, zb, a_src, a_tgt, NN);
    gat_kernel<<<nwgrid, 256, 0, stream>>>(rowptr2, csr_src2, a_src, a_tgt, zb, bg, Wf, bf, (float*)d_out);
}

// Round 4
// 491.908 us; speedup vs baseline: 1.1261x; 1.1261x over previous
//
#include <hip/hip_runtime.h>
#include <math.h>

// Problem constants
#define NN      50000
#define EE      800000
#define DIN     256
#define HF      128
#define RR      8
#define NHEADS  8
#define DHH     16
#define OUTC    3
#define M2      (NN * RR)                 // 400000 (t,rel) buckets
#define NB2     ((M2 + 255) / 256)        // 1563 scan blocks
#define CH2     ((NB2 + 255) / 256)       // 7 per-thread chunks in scan2

static inline int cdiv(long long a, int b) { return (int)((a + b - 1) / b); }

typedef __attribute__((ext_vector_type(8))) short short8;
typedef __attribute__((ext_vector_type(4))) float f32x4;

__device__ inline float bf2f(unsigned short u) {
    return __uint_as_float(((unsigned)u) << 16);
}
__device__ inline unsigned short f2bf(float f) {
    unsigned u = __float_as_uint(f);
    u += 0x7fffu + ((u >> 16) & 1u);   // RNE
    return (unsigned short)(u >> 16);
}

// ================= fused weight prep: transpose + hi/lo split, one dispatch =================
// regions (flat idx): Wp[0,32768) | W1[32768,163840) | root1[163840,180224)
//                     | W2[180224,311296) | root2[311296,327680) | Wg[327680,344064)
__global__ __launch_bounds__(256) void prep_weights(const float* __restrict__ Wp,
                                                    const float* __restrict__ W1,
                                                    const float* __restrict__ root1,
                                                    const float* __restrict__ W2,
                                                    const float* __restrict__ root2,
                                                    const float* __restrict__ Wg,
                                                    unsigned short* __restrict__ Wtp_hi,
                                                    unsigned short* __restrict__ Wtp_lo,
                                                    unsigned short* __restrict__ Wt1_hi,
                                                    unsigned short* __restrict__ Wt1_lo,
                                                    unsigned short* __restrict__ Wt2_hi,
                                                    unsigned short* __restrict__ Wt2_lo,
                                                    unsigned short* __restrict__ Wtg_hi,
                                                    unsigned short* __restrict__ Wtg_lo) {
    int i = blockIdx.x * 256 + threadIdx.x;
    if (i >= 344064) return;
    const float* src; unsigned short *dh, *dl; int k0, ldk, base;
    if (i < 32768)       { src = Wp;    dh = Wtp_hi; dl = Wtp_lo; k0 = 0;    ldk = 256;  base = 0; }
    else if (i < 163840) { src = W1;    dh = Wt1_hi; dl = Wt1_lo; k0 = 0;    ldk = 1152; base = 32768; }
    else if (i < 180224) { src = root1; dh = Wt1_hi; dl = Wt1_lo; k0 = 1024; ldk = 1152; base = 163840; }
    else if (i < 311296) { src = W2;    dh = Wt2_hi; dl = Wt2_lo; k0 = 0;    ldk = 1152; base = 180224; }
    else if (i < 327680) { src = root2; dh = Wt2_hi; dl = Wt2_lo; k0 = 1024; ldk = 1152; base = 311296; }
    else                 { src = Wg;    dh = Wtg_hi; dl = Wtg_lo; k0 = 0;    ldk = 128;  base = 327680; }
    int j = i - base;
    int k = j >> 7, n = j & 127;
    float f = src[(size_t)k * 128 + n];
    unsigned short hi = f2bf(f);
    unsigned short lo = f2bf(f - bf2f(hi));
    dh[(size_t)n * ldk + k0 + k] = hi;
    dl[(size_t)n * ldk + k0 + k] = lo;
}

// ================= CSR build, sorted by (tgt, rel) =================
__global__ __launch_bounds__(256) void count2_kernel(const int* __restrict__ tgt,
                                                     const int* __restrict__ et,
                                                     int* __restrict__ cnt2) {
    int i = blockIdx.x * 256 + threadIdx.x;
    if (i < EE) atomicAdd(&cnt2[tgt[i] * RR + et[i]], 1);
}

__global__ __launch_bounds__(256) void scan1_kernel(const int* __restrict__ cnt,
                                                    int* __restrict__ bsum, int n) {
    __shared__ int s[256];
    int t = threadIdx.x;
    int i = blockIdx.x * 256 + t;
    s[t] = (i < n) ? cnt[i] : 0;
    __syncthreads();
    for (int off = 128; off > 0; off >>= 1) {
        if (t < off) s[t] += s[t + off];
        __syncthreads();
    }
    if (t == 0) bsum[blockIdx.x] = s[0];
}

__global__ __launch_bounds__(256) void scan2_kernel(const int* __restrict__ bsum,
                                                    int* __restrict__ bbase,
                                                    int* __restrict__ tail,
                                                    int nb, int ch) {
    __shared__ int s[256];
    int t = threadIdx.x;
    int beg = t * ch;
    int end = beg + ch; if (end > nb) end = nb;
    int sum = 0;
    for (int i = beg; i < end; i++) sum += bsum[i];
    s[t] = sum;
    __syncthreads();
    for (int off = 1; off < 256; off <<= 1) {
        int u = (t >= off) ? s[t - off] : 0;
        __syncthreads();
        s[t] += u;
        __syncthreads();
    }
    int run = s[t] - sum;
    for (int i = beg; i < end; i++) {
        bbase[i] = run;
        run += bsum[i];
    }
    if (t == 255) *tail = s[255];
}

__global__ __launch_bounds__(256) void scan3_kernel(const int* __restrict__ cnt,
                                                    const int* __restrict__ bbase,
                                                    int* __restrict__ rowptr,
                                                    int* __restrict__ cursor, int n) {
    __shared__ int s[256];
    int t = threadIdx.x;
    int i = blockIdx.x * 256 + t;
    int v = (i < n) ? cnt[i] : 0;
    s[t] = v;
    __syncthreads();
    for (int off = 1; off < 256; off <<= 1) {
        int u = (t >= off) ? s[t - off] : 0;
        __syncthreads();
        s[t] += u;
        __syncthreads();
    }
    if (i < n) {
        int e = bbase[blockIdx.x] + s[t] - v;
        rowptr[i] = e;
        cursor[i] = e;
    }
}

__global__ __launch_bounds__(256) void fill2_kernel(const int* __restrict__ src,
                                                    const int* __restrict__ tgt,
                                                    const int* __restrict__ et,
                                                    int* __restrict__ cursor2,
                                                    int* __restrict__ csr_src2) {
    int e = blockIdx.x * 256 + threadIdx.x;
    if (e >= EE) return;
    int pos = atomicAdd(&cursor2[tgt[e] * RR + et[e]], 1);
    csr_src2[pos] = src[e];
}

// ================= generic MFMA GEMM (projection): 128-tile, 512 threads (8 waves) =================
// wave w: rows [64*(w>>2), +64), cols [32*(w&3), +32). acc[4][2].
#define BK 32
#define APAD 36

template <bool SPLITA, bool ACC, bool BIAS, bool RELU, bool BF16OUT>
__global__ __launch_bounds__(512) void gemm_mfma(const void* __restrict__ Av, int lda,
                                                 const unsigned short* __restrict__ Bthi,
                                                 const unsigned short* __restrict__ Btlo, int ldk,
                                                 float* __restrict__ C,
                                                 unsigned short* __restrict__ Cb,
                                                 const float* __restrict__ bias,
                                                 int M, int K) {
    __shared__ unsigned short Ah[128 * APAD];
    __shared__ unsigned short Al[(SPLITA ? 128 : 1) * APAD];
    __shared__ unsigned short Bh[128 * APAD];
    __shared__ unsigned short Bl[128 * APAD];
    const int tid  = threadIdx.x;
    const int m0   = blockIdx.x * 128;
    const int wr   = (tid >> 6) >> 2;     // 0..1
    const int wc   = (tid >> 6) & 3;      // 0..3
    const int lane = tid & 63;
    const int lrow = lane & 15;
    const int q    = lane >> 4;

    f32x4 acc[4][2];
#pragma unroll
    for (int t = 0; t < 4; t++)
#pragma unroll
        for (int c = 0; c < 2; c++) acc[t][c] = (f32x4){0.f, 0.f, 0.f, 0.f};

    const int srow  = tid >> 2;           // 0..127
    const int spart = (tid & 3) * 8;      // 0/8/16/24

    for (int k0 = 0; k0 < K; k0 += BK) {
        if (SPLITA) {
            const float* A = (const float*)Av;
            int gm = m0 + srow;
            float va[8];
            if (gm < M) {
                const float* ap = &A[(size_t)gm * lda + k0 + spart];
                float4 v0 = *reinterpret_cast<const float4*>(ap);
                float4 v1 = *reinterpret_cast<const float4*>(ap + 4);
                va[0] = v0.x; va[1] = v0.y; va[2] = v0.z; va[3] = v0.w;
                va[4] = v1.x; va[5] = v1.y; va[6] = v1.z; va[7] = v1.w;
            } else {
#pragma unroll
                for (int j = 0; j < 8; j++) va[j] = 0.f;
            }
            unsigned hw[4], lw[4];
#pragma unroll
            for (int j = 0; j < 4; j++) {
                unsigned short h0 = f2bf(va[2 * j]);
                unsigned short h1 = f2bf(va[2 * j + 1]);
                unsigned short l0 = f2bf(va[2 * j] - bf2f(h0));
                unsigned short l1 = f2bf(va[2 * j + 1] - bf2f(h1));
                hw[j] = (unsigned)h0 | ((unsigned)h1 << 16);
                lw[j] = (unsigned)l0 | ((unsigned)l1 << 16);
            }
            *reinterpret_cast<uint4*>(&Ah[srow * APAD + spart]) = make_uint4(hw[0], hw[1], hw[2], hw[3]);
            *reinterpret_cast<uint4*>(&Al[srow * APAD + spart]) = make_uint4(lw[0], lw[1], lw[2], lw[3]);
        } else {
            const unsigned short* A = (const unsigned short*)Av;
            int gm = m0 + srow;
            uint4 v = make_uint4(0u, 0u, 0u, 0u);
            if (gm < M) v = *reinterpret_cast<const uint4*>(&A[(size_t)gm * lda + k0 + spart]);
            *reinterpret_cast<uint4*>(&Ah[srow * APAD + spart]) = v;
        }
        {
            const unsigned short* bh = &Bthi[(size_t)srow * ldk + k0 + spart];
            const unsigned short* bl = &Btlo[(size_t)srow * ldk + k0 + spart];
            *reinterpret_cast<uint4*>(&Bh[srow * APAD + spart]) = *reinterpret_cast<const uint4*>(bh);
            *reinterpret_cast<uint4*>(&Bl[srow * APAD + spart]) = *reinterpret_cast<const uint4*>(bl);
        }
        __syncthreads();

        short8 ah[4], al[4];
#pragma unroll
        for (int t = 0; t < 4; t++) {
            ah[t] = *reinterpret_cast<const short8*>(&Ah[(wr * 64 + t * 16 + lrow) * APAD + q * 8]);
            if (SPLITA)
                al[t] = *reinterpret_cast<const short8*>(&Al[(wr * 64 + t * 16 + lrow) * APAD + q * 8]);
        }
#pragma unroll
        for (int cc = 0; cc < 2; cc++) {
            int cb = wc * 2 + cc;
            short8 bh = *reinterpret_cast<const short8*>(&Bh[(cb * 16 + lrow) * APAD + q * 8]);
            short8 bl = *reinterpret_cast<const short8*>(&Bl[(cb * 16 + lrow) * APAD + q * 8]);
#pragma unroll
            for (int t = 0; t < 4; t++) {
                acc[t][cc] = __builtin_amdgcn_mfma_f32_16x16x32_bf16(ah[t], bl, acc[t][cc], 0, 0, 0);
                if (SPLITA)
                    acc[t][cc] = __builtin_amdgcn_mfma_f32_16x16x32_bf16(al[t], bh, acc[t][cc], 0, 0, 0);
                acc[t][cc] = __builtin_amdgcn_mfma_f32_16x16x32_bf16(ah[t], bh, acc[t][cc], 0, 0, 0);
            }
        }
        __syncthreads();
    }

#pragma unroll
    for (int t = 0; t < 4; t++) {
#pragma unroll
        for (int r = 0; r < 4; r++) {
            int gm = m0 + wr * 64 + t * 16 + q * 4 + r;
            if (gm >= M) continue;
#pragma unroll
            for (int cc = 0; cc < 2; cc++) {
                int gn = (wc * 2 + cc) * 16 + lrow;
                float v = acc[t][cc][r];
                if (BIAS) v += bias[gn];
                if (ACC)  v += C[(size_t)gm * HF + gn];
                if (RELU) v = fmaxf(v, 0.f);
                C[(size_t)gm * HF + gn] = v;
                if (BF16OUT) Cb[(size_t)gm * HF + gn] = f2bf(v);
            }
        }
    }
}

// ================= merged RGCN layer GEMM: 128-tile, 512 threads (8 waves) =================
// hout = relu( aggb[N,1024] @ W[0:1024]^T + hin[N,128] @ root^T + bias ), + bf16 mirror.
__global__ __launch_bounds__(512) void gemm_rgcn(const unsigned short* __restrict__ aggb,
                                                 const float* __restrict__ hin,
                                                 const unsigned short* __restrict__ Bthi,
                                                 const unsigned short* __restrict__ Btlo,
                                                 float* __restrict__ hout,
                                                 unsigned short* __restrict__ hbout,
                                                 const float* __restrict__ bias, int M) {
    const int LDK = (RR + 1) * HF;  // 1152
    __shared__ unsigned short Ah[128 * APAD];
    __shared__ unsigned short Al[128 * APAD];
    __shared__ unsigned short Bh[128 * APAD];
    __shared__ unsigned short Bl[128 * APAD];
    const int tid  = threadIdx.x;
    const int m0   = blockIdx.x * 128;
    const int wr   = (tid >> 6) >> 2;     // 0..1
    const int wc   = (tid >> 6) & 3;      // 0..3
    const int lane = tid & 63;
    const int lrow = lane & 15;
    const int q    = lane >> 4;

    f32x4 acc[4][2];
#pragma unroll
    for (int t = 0; t < 4; t++)
#pragma unroll
        for (int c = 0; c < 2; c++) acc[t][c] = (f32x4){0.f, 0.f, 0.f, 0.f};

    const int srow  = tid >> 2;           // 0..127
    const int spart = (tid & 3) * 8;      // 0/8/16/24

    // ---- phase 1: K = 0..1024, A = aggb (bf16) ----
    for (int k0 = 0; k0 < RR * HF; k0 += BK) {
        {
            int gm = m0 + srow;
            uint4 v = make_uint4(0u, 0u, 0u, 0u);
            if (gm < M) v = *reinterpret_cast<const uint4*>(&aggb[(size_t)gm * (RR * HF) + k0 + spart]);
            *reinterpret_cast<uint4*>(&Ah[srow * APAD + spart]) = v;
        }
        {
            const unsigned short* bh = &Bthi[(size_t)srow * LDK + k0 + spart];
            const unsigned short* bl = &Btlo[(size_t)srow * LDK + k0 + spart];
            *reinterpret_cast<uint4*>(&Bh[srow * APAD + spart]) = *reinterpret_cast<const uint4*>(bh);
            *reinterpret_cast<uint4*>(&Bl[srow * APAD + spart]) = *reinterpret_cast<const uint4*>(bl);
        }
        __syncthreads();
        short8 ah[4];
#pragma unroll
        for (int t = 0; t < 4; t++)
            ah[t] = *reinterpret_cast<const short8*>(&Ah[(wr * 64 + t * 16 + lrow) * APAD + q * 8]);
#pragma unroll
        for (int cc = 0; cc < 2; cc++) {
            int cb = wc * 2 + cc;
            short8 bh = *reinterpret_cast<const short8*>(&Bh[(cb * 16 + lrow) * APAD + q * 8]);
            short8 bl = *reinterpret_cast<const short8*>(&Bl[(cb * 16 + lrow) * APAD + q * 8]);
#pragma unroll
            for (int t = 0; t < 4; t++) {
                acc[t][cc] = __builtin_amdgcn_mfma_f32_16x16x32_bf16(ah[t], bl, acc[t][cc], 0, 0, 0);
                acc[t][cc] = __builtin_amdgcn_mfma_f32_16x16x32_bf16(ah[t], bh, acc[t][cc], 0, 0, 0);
            }
        }
        __syncthreads();
    }

    // ---- phase 2: K = 1024..1152, A = hin (fp32 split) ----
    for (int k0 = 0; k0 < HF; k0 += BK) {
        {
            int gm = m0 + srow;
            float va[8];
            if (gm < M) {
                const float* ap = &hin[(size_t)gm * HF + k0 + spart];
                float4 v0 = *reinterpret_cast<const float4*>(ap);
                float4 v1 = *reinterpret_cast<const float4*>(ap + 4);
                va[0] = v0.x; va[1] = v0.y; va[2] = v0.z; va[3] = v0.w;
                va[4] = v1.x; va[5] = v1.y; va[6] = v1.z; va[7] = v1.w;
            } else {
#pragma unroll
                for (int j = 0; j < 8; j++) va[j] = 0.f;
            }
            unsigned hw[4], lw[4];
#pragma unroll
            for (int j = 0; j < 4; j++) {
                unsigned short h0 = f2bf(va[2 * j]);
                unsigned short h1 = f2bf(va[2 * j + 1]);
                unsigned short l0 = f2bf(va[2 * j] - bf2f(h0));
                unsigned short l1 = f2bf(va[2 * j + 1] - bf2f(h1));
                hw[j] = (unsigned)h0 | ((unsigned)h1 << 16);
                lw[j] = (unsigned)l0 | ((unsigned)l1 << 16);
            }
            *reinterpret_cast<uint4*>(&Ah[srow * APAD + spart]) = make_uint4(hw[0], hw[1], hw[2], hw[3]);
            *reinterpret_cast<uint4*>(&Al[srow * APAD + spart]) = make_uint4(lw[0], lw[1], lw[2], lw[3]);
        }
        {
            const unsigned short* bh = &Bthi[(size_t)srow * LDK + RR * HF + k0 + spart];
            const unsigned short* bl = &Btlo[(size_t)srow * LDK + RR * HF + k0 + spart];
            *reinterpret_cast<uint4*>(&Bh[srow * APAD + spart]) = *reinterpret_cast<const uint4*>(bh);
            *reinterpret_cast<uint4*>(&Bl[srow * APAD + spart]) = *reinterpret_cast<const uint4*>(bl);
        }
        __syncthreads();
        short8 ah[4], al[4];
#pragma unroll
        for (int t = 0; t < 4; t++) {
            ah[t] = *reinterpret_cast<const short8*>(&Ah[(wr * 64 + t * 16 + lrow) * APAD + q * 8]);
            al[t] = *reinterpret_cast<const short8*>(&Al[(wr * 64 + t * 16 + lrow) * APAD + q * 8]);
        }
#pragma unroll
        for (int cc = 0; cc < 2; cc++) {
            int cb = wc * 2 + cc;
            short8 bh = *reinterpret_cast<const short8*>(&Bh[(cb * 16 + lrow) * APAD + q * 8]);
            short8 bl = *reinterpret_cast<const short8*>(&Bl[(cb * 16 + lrow) * APAD + q * 8]);
#pragma unroll
            for (int t = 0; t < 4; t++) {
                acc[t][cc] = __builtin_amdgcn_mfma_f32_16x16x32_bf16(ah[t], bl, acc[t][cc], 0, 0, 0);
                acc[t][cc] = __builtin_amdgcn_mfma_f32_16x16x32_bf16(al[t], bh, acc[t][cc], 0, 0, 0);
                acc[t][cc] = __builtin_amdgcn_mfma_f32_16x16x32_bf16(ah[t], bh, acc[t][cc], 0, 0, 0);
            }
        }
        __syncthreads();
    }

#pragma unroll
    for (int t = 0; t < 4; t++) {
#pragma unroll
        for (int r = 0; r < 4; r++) {
            int gm = m0 + wr * 64 + t * 16 + q * 4 + r;
            if (gm >= M) continue;
#pragma unroll
            for (int cc = 0; cc < 2; cc++) {
                int gn = (wc * 2 + cc) * 16 + lrow;
                float v = fmaxf(acc[t][cc][r] + bias[gn], 0.f);
                hout[(size_t)gm * HF + gn] = v;
                hbout[(size_t)gm * HF + gn] = f2bf(v);
            }
        }
    }
}

// ================= z GEMM with fused attention scores =================
__global__ __launch_bounds__(256) void gemm_z(const float* __restrict__ hin,
                                              const unsigned short* __restrict__ Bthi,
                                              const unsigned short* __restrict__ Btlo,
                                              const float* __restrict__ att,
                                              unsigned short* __restrict__ zb,
                                              float* __restrict__ a_src,
                                              float* __restrict__ a_tgt, int M) {
    __shared__ unsigned short Ah[128 * APAD];
    __shared__ unsigned short Al[128 * APAD];
    __shared__ unsigned short Bh[128 * APAD];
    __shared__ unsigned short Bl[128 * APAD];
    const int tid  = threadIdx.x;
    const int m0   = blockIdx.x * 128;
    const int w    = tid >> 6;
    const int lane = tid & 63;
    const int lrow = lane & 15;
    const int q    = lane >> 4;

    f32x4 acc[2][8];
#pragma unroll
    for (int t = 0; t < 2; t++)
#pragma unroll
        for (int c = 0; c < 8; c++) acc[t][c] = (f32x4){0.f, 0.f, 0.f, 0.f};

    const int srow  = tid >> 1;
    const int spart = (tid & 1) * 16;

    for (int k0 = 0; k0 < HF; k0 += BK) {
        {
            int gm = m0 + srow;
            float va[16];
            if (gm < M) {
                const float* ap = &hin[(size_t)gm * HF + k0 + spart];
#pragma unroll
                for (int j = 0; j < 4; j++) {
                    float4 v = *reinterpret_cast<const float4*>(ap + j * 4);
                    va[j * 4 + 0] = v.x; va[j * 4 + 1] = v.y; va[j * 4 + 2] = v.z; va[j * 4 + 3] = v.w;
                }
            } else {
#pragma unroll
                for (int j = 0; j < 16; j++) va[j] = 0.f;
            }
            unsigned hw[8], lw[8];
#pragma unroll
            for (int j = 0; j < 8; j++) {
                unsigned short h0 = f2bf(va[2 * j]);
                unsigned short h1 = f2bf(va[2 * j + 1]);
                unsigned short l0 = f2bf(va[2 * j] - bf2f(h0));
                unsigned short l1 = f2bf(va[2 * j + 1] - bf2f(h1));
                hw[j] = (unsigned)h0 | ((unsigned)h1 << 16);
                lw[j] = (unsigned)l0 | ((unsigned)l1 << 16);
            }
            *reinterpret_cast<uint4*>(&Ah[srow * APAD + spart])     = make_uint4(hw[0], hw[1], hw[2], hw[3]);
            *reinterpret_cast<uint4*>(&Ah[srow * APAD + spart + 8]) = make_uint4(hw[4], hw[5], hw[6], hw[7]);
            *reinterpret_cast<uint4*>(&Al[srow * APAD + spart])     = make_uint4(lw[0], lw[1], lw[2], lw[3]);
            *reinterpret_cast<uint4*>(&Al[srow * APAD + spart + 8]) = make_uint4(lw[4], lw[5], lw[6], lw[7]);
        }
        {
            const unsigned short* bh = &Bthi[(size_t)srow * HF + k0 + spart];
            const unsigned short* bl = &Btlo[(size_t)srow * HF + k0 + spart];
            *reinterpret_cast<uint4*>(&Bh[srow * APAD + spart])     = *reinterpret_cast<const uint4*>(bh);
            *reinterpret_cast<uint4*>(&Bh[srow * APAD + spart + 8]) = *reinterpret_cast<const uint4*>(bh + 8);
            *reinterpret_cast<uint4*>(&Bl[srow * APAD + spart])     = *reinterpret_cast<const uint4*>(bl);
            *reinterpret_cast<uint4*>(&Bl[srow * APAD + spart + 8]) = *reinterpret_cast<const uint4*>(bl + 8);
        }
        __syncthreads();
        short8 ah[2], al[2];
#pragma unroll
        for (int t = 0; t < 2; t++) {
            ah[t] = *reinterpret_cast<const short8*>(&Ah[(w * 32 + t * 16 + lrow) * APAD + q * 8]);
            al[t] = *reinterpret_cast<const short8*>(&Al[(w * 32 + t * 16 + lrow) * APAD + q * 8]);
        }
#pragma unroll
        for (int c = 0; c < 8; c++) {
            short8 bh = *reinterpret_cast<const short8*>(&Bh[(c * 16 + lrow) * APAD + q * 8]);
            short8 bl = *reinterpret_cast<const short8*>(&Bl[(c * 16 + lrow) * APAD + q * 8]);
#pragma unroll
            for (int t = 0; t < 2; t++) {
                acc[t][c] = __builtin_amdgcn_mfma_f32_16x16x32_bf16(ah[t], bl, acc[t][c], 0, 0, 0);
                acc[t][c] = __builtin_amdgcn_mfma_f32_16x16x32_bf16(al[t], bh, acc[t][c], 0, 0, 0);
                acc[t][c] = __builtin_amdgcn_mfma_f32_16x16x32_bf16(ah[t], bh, acc[t][c], 0, 0, 0);
            }
        }
        __syncthreads();
    }

    float att_s[8], att_t[8];
#pragma unroll
    for (int c = 0; c < 8; c++) {
        att_s[c] = att[c * 32 + lrow];
        att_t[c] = att[c * 32 + 16 + lrow];
    }

#pragma unroll
    for (int t = 0; t < 2; t++) {
#pragma unroll
        for (int r = 0; r < 4; r++) {
            int gm = m0 + w * 32 + t * 16 + q * 4 + r;
            if (gm >= M) continue;
#pragma unroll
            for (int c = 0; c < 8; c++) {
                int gn = c * 16 + lrow;
                float v = acc[t][c][r];
                zb[(size_t)gm * HF + gn] = f2bf(v);
                float ps = v * att_s[c];
                float pt = v * att_t[c];
#pragma unroll
                for (int off = 1; off < 16; off <<= 1) {
                    ps += __shfl_xor(ps, off);
                    pt += __shfl_xor(pt, off);
                }
                if (lrow == 0) {
                    a_src[(size_t)gm * NHEADS + c] = ps;
                    a_tgt[(size_t)gm * NHEADS + c] = pt;
                }
            }
        }
    }
}

// ================= RGCN gather: all 8 relations concurrent per wave =================
__device__ inline void acc8(float* a, uint4 v) {
    a[0] += bf2f((unsigned short)(v.x & 0xffffu));
    a[1] += bf2f((unsigned short)(v.x >> 16));
    a[2] += bf2f((unsigned short)(v.y & 0xffffu));
    a[3] += bf2f((unsigned short)(v.y >> 16));
    a[4] += bf2f((unsigned short)(v.z & 0xffffu));
    a[5] += bf2f((unsigned short)(v.z >> 16));
    a[6] += bf2f((unsigned short)(v.w & 0xffffu));
    a[7] += bf2f((unsigned short)(v.w >> 16));
}

__global__ __launch_bounds__(256) void rgcn_agg_sorted(const unsigned short* __restrict__ hb,
                                                       const int* __restrict__ rowptr2,
                                                       const int* __restrict__ csr_src2,
                                                       unsigned short* __restrict__ agg) {
    int w = (blockIdx.x * 256 + threadIdx.x) >> 6;
    if (w >= NN) return;
    int lane = threadIdx.x & 63;
    int r    = lane >> 3;          // relation handled by this lane's group
    int cg   = (lane & 7) * 16;    // 16 columns (32 B) of the 128-wide row
    int b8   = w * RR;

    int rp  = rowptr2[b8 + (lane < 9 ? lane : 8)];
    int beg = __shfl(rp, r);
    int end = __shfl(rp, r + 1);

    float a[16];
#pragma unroll
    for (int j = 0; j < 16; j++) a[j] = 0.f;

    int e = beg;
    for (; e + 1 < end; e += 2) {
        int s0 = csr_src2[e];
        int s1 = csr_src2[e + 1];
        const uint4* p0 = reinterpret_cast<const uint4*>(&hb[(size_t)s0 * HF + cg]);
        const uint4* p1 = reinterpret_cast<const uint4*>(&hb[(size_t)s1 * HF + cg]);
        uint4 v00 = p0[0];
        uint4 v01 = p0[1];
        uint4 v10 = p1[0];
        uint4 v11 = p1[1];
        acc8(a,     v00);
        acc8(a + 8, v01);
        acc8(a,     v10);
        acc8(a + 8, v11);
    }
    if (e < end) {
        int s0 = csr_src2[e];
        const uint4* p0 = reinterpret_cast<const uint4*>(&hb[(size_t)s0 * HF + cg]);
        uint4 v00 = p0[0];
        uint4 v01 = p0[1];
        acc8(a,     v00);
        acc8(a + 8, v01);
    }

    int n = end - beg;
    float inv = 1.f / (float)(n > 1 ? n : 1);
    unsigned ow[8];
#pragma unroll
    for (int j = 0; j < 8; j++) {
        ow[j] = (unsigned)f2bf(a[2 * j] * inv) | ((unsigned)f2bf(a[2 * j + 1] * inv) << 16);
    }
    unsigned short* o = &agg[(size_t)w * (RR * HF) + r * HF + cg];
    *reinterpret_cast<uint4*>(o)     = make_uint4(ow[0], ow[1], ow[2], ow[3]);
    *reinterpret_cast<uint4*>(o + 8) = make_uint4(ow[4], ow[5], ow[6], ow[7]);
}

// ================= GAT: two-pass, chunked-shuffle weights + half-split accumulate =================
__global__ __launch_bounds__(256) void gat_kernel(const int* __restrict__ rowptr2,
                                                  const int* __restrict__ csr_src2,
                                                  const float* __restrict__ a_src,
                                                  const float* __restrict__ a_tgt,
                                                  const unsigned short* __restrict__ zb,
                                                  const float* __restrict__ bg,
                                                  const float* __restrict__ Wf,
                                                  const float* __restrict__ bf,
                                                  float* __restrict__ out) {
    int w = (blockIdx.x * 256 + threadIdx.x) >> 6;
    if (w >= NN) return;
    int lane = threadIdx.x & 63;
    int beg = rowptr2[w * RR], end = rowptr2[w * RR + RR];

    // ---- pass A: segment max, 8 edges x 8 heads in parallel ----
    int hdA = lane & 7;
    int e8  = lane >> 3;
    float atA = a_tgt[w * NHEADS + hdA];
    float m = -1e30f;
    for (int e = beg + e8; e < end; e += 8) {
        int s = csr_src2[e];
        float a = a_src[s * NHEADS + hdA] + atA;
        a = a > 0.f ? a : 0.2f * a;
        m = fmaxf(m, a);
    }
    m = fmaxf(m, __shfl_xor(m, 8));
    m = fmaxf(m, __shfl_xor(m, 16));
    m = fmaxf(m, __shfl_xor(m, 32));

    // ---- pass B: chunked weights + half-split accumulate ----
    int half = lane >> 5;
    int l32  = lane & 31;
    int hd   = l32 >> 2;
    int c0   = l32 * 4;

    float l = 0.f;
    float ax0 = 0.f, ax1 = 0.f, ax2 = 0.f, ax3 = 0.f;

    for (int e0 = beg; e0 < end; e0 += 8) {
        int eA = e0 + e8;
        float wA = 0.f;
        int   sA = 0;
        if (eA < end) {
            sA = csr_src2[eA];
            float a = a_src[sA * NHEADS + hdA] + atA;
            a = a > 0.f ? a : 0.2f * a;
            wA = __expf(a - m);
        }
#pragma unroll
        for (int j = 0; j < 4; j++) {
            int idx  = (2 * j + half) * 8 + hd;
            float wv = __shfl(wA, idx);
            int   sv = __shfl(sA, idx);
            uint2 z = *reinterpret_cast<const uint2*>(&zb[(size_t)sv * HF + c0]);
            l   += wv;
            ax0 += bf2f((unsigned short)(z.x & 0xffffu)) * wv;
            ax1 += bf2f((unsigned short)(z.x >> 16)) * wv;
            ax2 += bf2f((unsigned short)(z.y & 0xffffu)) * wv;
            ax3 += bf2f((unsigned short)(z.y >> 16)) * wv;
        }
    }
    l   += __shfl_xor(l, 32);
    ax0 += __shfl_xor(ax0, 32);
    ax1 += __shfl_xor(ax1, 32);
    ax2 += __shfl_xor(ax2, 32);
    ax3 += __shfl_xor(ax3, 32);

    float inv = 1.f / fmaxf(l, 1e-16f);
    float v0 = ax0 * inv + bg[c0];
    float v1 = ax1 * inv + bg[c0 + 1];
    float v2 = ax2 * inv + bg[c0 + 2];
    float v3 = ax3 * inv + bg[c0 + 3];

    float p0 = v0 * Wf[c0 * 3 + 0] + v1 * Wf[(c0 + 1) * 3 + 0]
             + v2 * Wf[(c0 + 2) * 3 + 0] + v3 * Wf[(c0 + 3) * 3 + 0];
    float p1 = v0 * Wf[c0 * 3 + 1] + v1 * Wf[(c0 + 1) * 3 + 1]
             + v2 * Wf[(c0 + 2) * 3 + 1] + v3 * Wf[(c0 + 3) * 3 + 1];
    float p2 = v0 * Wf[c0 * 3 + 2] + v1 * Wf[(c0 + 1) * 3 + 2]
             + v2 * Wf[(c0 + 2) * 3 + 2] + v3 * Wf[(c0 + 3) * 3 + 2];
#pragma unroll
    for (int off = 16; off > 0; off >>= 1) {
        p0 += __shfl_xor(p0, off);
        p1 += __shfl_xor(p1, off);
        p2 += __shfl_xor(p2, off);
    }
    if (lane == 0) {
        float l0v = p0 + bf[0], l1v = p1 + bf[1], l2v = p2 + bf[2];
        float mm = fmaxf(l0v, fmaxf(l1v, l2v));
        float lse = mm + logf(expf(l0v - mm) + expf(l1v - mm) + expf(l2v - mm));
        out[(size_t)w * 3 + 0] = l0v - lse;
        out[(size_t)w * 3 + 1] = l1v - lse;
        out[(size_t)w * 3 + 2] = l2v - lse;
    }
}

// ================= launch =================
extern "C" void kernel_launch(void* const* d_in, const int* in_sizes, int n_in,
                              void* d_out, int out_size, void* d_ws, size_t ws_size,
                              hipStream_t stream) {
    const float* x     = (const float*)d_in[0];
    const int*   ei    = (const int*)d_in[1];
    const int*   etype = (const int*)d_in[2];
    const float* Wp    = (const float*)d_in[3];
    const float* bp    = (const float*)d_in[4];
    const float* W1    = (const float*)d_in[5];
    const float* root1 = (const float*)d_in[6];
    const float* b1    = (const float*)d_in[7];
    const float* W2    = (const float*)d_in[8];
    const float* root2 = (const float*)d_in[9];
    const float* b2    = (const float*)d_in[10];
    const float* Wg    = (const float*)d_in[11];
    const float* att   = (const float*)d_in[12];
    const float* bg    = (const float*)d_in[13];
    const float* Wf    = (const float*)d_in[14];
    const float* bf    = (const float*)d_in[15];
    (void)in_sizes; (void)n_in; (void)out_size; (void)ws_size;

    const int* srcv = ei;
    const int* tgtv = ei + EE;

    // ---- workspace layout (bytes), ~185.4 MB ----
    char* base = (char*)d_ws;
    unsigned short* aggb = (unsigned short*)(base + 0);   // N*1024*2 = 102,400,000
    int* cnt2    = (int*)(base + 96000000);               // 1,600,000 (aliased, dead before walk 1)
    int* cursor2 = (int*)(base + 98000000);               // 1,600,000
    int* bsum2   = (int*)(base + 99700000);               // 6,256
    int* bbase2  = (int*)(base + 99800000);               // 6,256
    unsigned short* zb = (unsigned short*)(base + 0);     // 12,800,000 (GAT phase)
    float* a_src = (float*)(base + 12800000);             // 1,600,000
    float* a_tgt = (float*)(base + 14400000);             // 1,600,000
    float* h1    = (float*)(base + 102400000);            // 25,600,000
    float* h2    = (float*)(base + 128000000);            // 25,600,000
    unsigned short* h1b = (unsigned short*)(base + 153600000); // 12,800,000
    unsigned short* h2b = (unsigned short*)(base + 166400000); // 12,800,000
    int* csr_src2 = (int*)(base + 179200000);             // 3,200,000
    int* rowptr2  = (int*)(base + 182400000);             // 1,600,016
    unsigned short* Wtp_hi = (unsigned short*)(base + 184000016); // 65,536
    unsigned short* Wtp_lo = (unsigned short*)(base + 184065552); // 65,536
    unsigned short* Wt1_hi = (unsigned short*)(base + 184131088); // 294,912
    unsigned short* Wt1_lo = (unsigned short*)(base + 184426000); // 294,912
    unsigned short* Wt2_hi = (unsigned short*)(base + 184720912); // 294,912
    unsigned short* Wt2_lo = (unsigned short*)(base + 185015824); // 294,912
    unsigned short* Wtg_hi = (unsigned short*)(base + 185310736); // 32,768
    unsigned short* Wtg_lo = (unsigned short*)(base + 185343504); // 32,768

    // ---- weight prep: one dispatch ----
    prep_weights<<<cdiv(344064, 256), 256, 0, stream>>>(
        Wp, W1, root1, W2, root2, Wg,
        Wtp_hi, Wtp_lo, Wt1_hi, Wt1_lo, Wt2_hi, Wt2_lo, Wtg_hi, Wtg_lo);

    // ---- CSR build, sorted by (tgt, rel) ----
    hipMemsetAsync(cnt2, 0, (size_t)M2 * 4, stream);
    count2_kernel<<<cdiv(EE, 256), 256, 0, stream>>>(tgtv, etype, cnt2);
    scan1_kernel<<<NB2, 256, 0, stream>>>(cnt2, bsum2, M2);
    scan2_kernel<<<1, 256, 0, stream>>>(bsum2, bbase2, &rowptr2[M2], NB2, CH2);
    scan3_kernel<<<NB2, 256, 0, stream>>>(cnt2, bbase2, rowptr2, cursor2, M2);
    fill2_kernel<<<cdiv(EE, 256), 256, 0, stream>>>(srcv, tgtv, etype, cursor2, csr_src2);

    const int ggrid  = cdiv(NN, 128);   // 391
    const int nwgrid = cdiv(NN, 4);

    // ---- projection: h1 = x @ Wp + bp (fp32-effective) + h1b mirror ----
    gemm_mfma<true, false, true, false, true><<<ggrid, 512, 0, stream>>>(
        x, DIN, Wtp_hi, Wtp_lo, DIN, h1, h1b, bp, NN, DIN);

    // ---- RGCN layer 1: h1 -> h2 ----
    rgcn_agg_sorted<<<nwgrid, 256, 0, stream>>>(h1b, rowptr2, csr_src2, aggb);
    gemm_rgcn<<<ggrid, 512, 0, stream>>>(aggb, h1, Wt1_hi, Wt1_lo, h2, h2b, b1, NN);

    // ---- RGCN layer 2: h2 -> h1 ----
    rgcn_agg_sorted<<<nwgrid, 256, 0, stream>>>(h2b, rowptr2, csr_src2, aggb);
    gemm_rgcn<<<ggrid, 512, 0, stream>>>(aggb, h2, Wt2_hi, Wt2_lo, h1, h1b, b2, NN);

    // ---- GAT: z GEMM (fused scores) + two-pass softmax-aggregate ----
    gemm_z<<<ggrid, 256, 0, stream>>>(h1, Wtg_hi, Wtg_lo, att, zb, a_src, a_tgt, NN);
    gat_kernel<<<nwgrid, 256, 0, stream>>>(rowptr2, csr_src2, a_src, a_tgt, zb, bg, Wf, bf, (float*)d_out);
}

// Round 5
// 482.281 us; speedup vs baseline: 1.1486x; 1.0200x over previous
//
#include <hip/hip_runtime.h>
#include <math.h>

// Problem constants
#define NN      50000
#define EE      800000
#define DIN     256
#define HF      128
#define RR      8
#define NHEADS  8
#define DHH     16
#define OUTC    3
#define M2      (NN * RR)                 // 400000 (t,rel) buckets
#define NB2     ((M2 + 255) / 256)        // 1563 scan blocks
#define CH2     ((NB2 + 255) / 256)       // 7 per-thread chunks in scan2

static inline int cdiv(long long a, int b) { return (int)((a + b - 1) / b); }

typedef __attribute__((ext_vector_type(8))) short short8;
typedef __attribute__((ext_vector_type(4))) float f32x4;

__device__ inline float bf2f(unsigned short u) {
    return __uint_as_float(((unsigned)u) << 16);
}
__device__ inline unsigned short f2bf(float f) {
    unsigned u = __float_as_uint(f);
    u += 0x7fffu + ((u >> 16) & 1u);   // RNE
    return (unsigned short)(u >> 16);
}

// ================= fused weight prep: transpose + hi/lo split, one dispatch =================
__global__ __launch_bounds__(256) void prep_weights(const float* __restrict__ Wp,
                                                    const float* __restrict__ W1,
                                                    const float* __restrict__ root1,
                                                    const float* __restrict__ W2,
                                                    const float* __restrict__ root2,
                                                    const float* __restrict__ Wg,
                                                    unsigned short* __restrict__ Wtp_hi,
                                                    unsigned short* __restrict__ Wtp_lo,
                                                    unsigned short* __restrict__ Wt1_hi,
                                                    unsigned short* __restrict__ Wt1_lo,
                                                    unsigned short* __restrict__ Wt2_hi,
                                                    unsigned short* __restrict__ Wt2_lo,
                                                    unsigned short* __restrict__ Wtg_hi,
                                                    unsigned short* __restrict__ Wtg_lo) {
    int i = blockIdx.x * 256 + threadIdx.x;
    if (i >= 344064) return;
    const float* src; unsigned short *dh, *dl; int k0, ldk, base;
    if (i < 32768)       { src = Wp;    dh = Wtp_hi; dl = Wtp_lo; k0 = 0;    ldk = 256;  base = 0; }
    else if (i < 163840) { src = W1;    dh = Wt1_hi; dl = Wt1_lo; k0 = 0;    ldk = 1152; base = 32768; }
    else if (i < 180224) { src = root1; dh = Wt1_hi; dl = Wt1_lo; k0 = 1024; ldk = 1152; base = 163840; }
    else if (i < 311296) { src = W2;    dh = Wt2_hi; dl = Wt2_lo; k0 = 0;    ldk = 1152; base = 180224; }
    else if (i < 327680) { src = root2; dh = Wt2_hi; dl = Wt2_lo; k0 = 1024; ldk = 1152; base = 311296; }
    else                 { src = Wg;    dh = Wtg_hi; dl = Wtg_lo; k0 = 0;    ldk = 128;  base = 327680; }
    int j = i - base;
    int k = j >> 7, n = j & 127;
    float f = src[(size_t)k * 128 + n];
    unsigned short hi = f2bf(f);
    unsigned short lo = f2bf(f - bf2f(hi));
    dh[(size_t)n * ldk + k0 + k] = hi;
    dl[(size_t)n * ldk + k0 + k] = lo;
}

// ================= CSR build, sorted by (tgt, rel) =================
__global__ __launch_bounds__(256) void count2_kernel(const int* __restrict__ tgt,
                                                     const int* __restrict__ et,
                                                     int* __restrict__ cnt2) {
    int i = blockIdx.x * 256 + threadIdx.x;
    if (i < EE) atomicAdd(&cnt2[tgt[i] * RR + et[i]], 1);
}

__global__ __launch_bounds__(256) void scan1_kernel(const int* __restrict__ cnt,
                                                    int* __restrict__ bsum, int n) {
    __shared__ int s[256];
    int t = threadIdx.x;
    int i = blockIdx.x * 256 + t;
    s[t] = (i < n) ? cnt[i] : 0;
    __syncthreads();
    for (int off = 128; off > 0; off >>= 1) {
        if (t < off) s[t] += s[t + off];
        __syncthreads();
    }
    if (t == 0) bsum[blockIdx.x] = s[0];
}

__global__ __launch_bounds__(256) void scan2_kernel(const int* __restrict__ bsum,
                                                    int* __restrict__ bbase,
                                                    int* __restrict__ tail,
                                                    int nb, int ch) {
    __shared__ int s[256];
    int t = threadIdx.x;
    int beg = t * ch;
    int end = beg + ch; if (end > nb) end = nb;
    int sum = 0;
    for (int i = beg; i < end; i++) sum += bsum[i];
    s[t] = sum;
    __syncthreads();
    for (int off = 1; off < 256; off <<= 1) {
        int u = (t >= off) ? s[t - off] : 0;
        __syncthreads();
        s[t] += u;
        __syncthreads();
    }
    int run = s[t] - sum;
    for (int i = beg; i < end; i++) {
        bbase[i] = run;
        run += bsum[i];
    }
    if (t == 255) *tail = s[255];
}

__global__ __launch_bounds__(256) void scan3_kernel(const int* __restrict__ cnt,
                                                    const int* __restrict__ bbase,
                                                    int* __restrict__ rowptr,
                                                    int* __restrict__ cursor, int n) {
    __shared__ int s[256];
    int t = threadIdx.x;
    int i = blockIdx.x * 256 + t;
    int v = (i < n) ? cnt[i] : 0;
    s[t] = v;
    __syncthreads();
    for (int off = 1; off < 256; off <<= 1) {
        int u = (t >= off) ? s[t - off] : 0;
        __syncthreads();
        s[t] += u;
        __syncthreads();
    }
    if (i < n) {
        int e = bbase[blockIdx.x] + s[t] - v;
        rowptr[i] = e;
        cursor[i] = e;
    }
}

__global__ __launch_bounds__(256) void fill2_kernel(const int* __restrict__ src,
                                                    const int* __restrict__ tgt,
                                                    const int* __restrict__ et,
                                                    int* __restrict__ cursor2,
                                                    int* __restrict__ csr_src2) {
    int e = blockIdx.x * 256 + threadIdx.x;
    if (e >= EE) return;
    int pos = atomicAdd(&cursor2[tgt[e] * RR + et[e]], 1);
    csr_src2[pos] = src[e];
}

// ================= generic MFMA GEMM (projection): 128-tile, 512 threads, T14 pipelined =================
// wave w: rows [64*(w>>2), +64), cols [32*(w&3), +32). acc[4][2].
// K-loop: issue tile t+1's global loads BEFORE computing tile t; waitcnt+ds_write after the
// compute barrier — global-load latency hides under MFMA instead of serializing each step.
#define BK 32
#define APAD 36

template <bool SPLITA, bool ACC, bool BIAS, bool RELU, bool BF16OUT>
__global__ __launch_bounds__(512) void gemm_mfma(const void* __restrict__ Av, int lda,
                                                 const unsigned short* __restrict__ Bthi,
                                                 const unsigned short* __restrict__ Btlo, int ldk,
                                                 float* __restrict__ C,
                                                 unsigned short* __restrict__ Cb,
                                                 const float* __restrict__ bias,
                                                 int M, int K) {
    __shared__ unsigned short Ah[128 * APAD];
    __shared__ unsigned short Al[(SPLITA ? 128 : 1) * APAD];
    __shared__ unsigned short Bh[128 * APAD];
    __shared__ unsigned short Bl[128 * APAD];
    const int tid  = threadIdx.x;
    const int m0   = blockIdx.x * 128;
    const int wr   = (tid >> 6) >> 2;     // 0..1
    const int wc   = (tid >> 6) & 3;      // 0..3
    const int lane = tid & 63;
    const int lrow = lane & 15;
    const int q    = lane >> 4;

    f32x4 acc[4][2];
#pragma unroll
    for (int t = 0; t < 4; t++)
#pragma unroll
        for (int c = 0; c < 2; c++) acc[t][c] = (f32x4){0.f, 0.f, 0.f, 0.f};

    const int srow  = tid >> 2;           // 0..127
    const int spart = (tid & 3) * 8;      // 0/8/16/24
    const int gm    = m0 + srow;

    // staged regs
    float rva[8];
    uint4 rvau = make_uint4(0u, 0u, 0u, 0u);
    uint4 rvbh, rvbl;

    auto load_t = [&](int k0) {
        if (SPLITA) {
            const float* A = (const float*)Av;
            if (gm < M) {
                const float* ap = &A[(size_t)gm * lda + k0 + spart];
                float4 v0 = *reinterpret_cast<const float4*>(ap);
                float4 v1 = *reinterpret_cast<const float4*>(ap + 4);
                rva[0] = v0.x; rva[1] = v0.y; rva[2] = v0.z; rva[3] = v0.w;
                rva[4] = v1.x; rva[5] = v1.y; rva[6] = v1.z; rva[7] = v1.w;
            } else {
#pragma unroll
                for (int j = 0; j < 8; j++) rva[j] = 0.f;
            }
        } else {
            const unsigned short* A = (const unsigned short*)Av;
            rvau = make_uint4(0u, 0u, 0u, 0u);
            if (gm < M) rvau = *reinterpret_cast<const uint4*>(&A[(size_t)gm * lda + k0 + spart]);
        }
        rvbh = *reinterpret_cast<const uint4*>(&Bthi[(size_t)srow * ldk + k0 + spart]);
        rvbl = *reinterpret_cast<const uint4*>(&Btlo[(size_t)srow * ldk + k0 + spart]);
    };
    auto write_t = [&]() {
        if (SPLITA) {
            unsigned hw[4], lw[4];
#pragma unroll
            for (int j = 0; j < 4; j++) {
                unsigned short h0 = f2bf(rva[2 * j]);
                unsigned short h1 = f2bf(rva[2 * j + 1]);
                unsigned short l0 = f2bf(rva[2 * j] - bf2f(h0));
                unsigned short l1 = f2bf(rva[2 * j + 1] - bf2f(h1));
                hw[j] = (unsigned)h0 | ((unsigned)h1 << 16);
                lw[j] = (unsigned)l0 | ((unsigned)l1 << 16);
            }
            *reinterpret_cast<uint4*>(&Ah[srow * APAD + spart]) = make_uint4(hw[0], hw[1], hw[2], hw[3]);
            *reinterpret_cast<uint4*>(&Al[srow * APAD + spart]) = make_uint4(lw[0], lw[1], lw[2], lw[3]);
        } else {
            *reinterpret_cast<uint4*>(&Ah[srow * APAD + spart]) = rvau;
        }
        *reinterpret_cast<uint4*>(&Bh[srow * APAD + spart]) = rvbh;
        *reinterpret_cast<uint4*>(&Bl[srow * APAD + spart]) = rvbl;
    };

    const int NT = K / BK;
    load_t(0); write_t(); __syncthreads();
    for (int t = 0; t < NT; t++) {
        if (t + 1 < NT) load_t((t + 1) * BK);   // async, overlaps compute below

        short8 ah[4], al[4];
#pragma unroll
        for (int tt = 0; tt < 4; tt++) {
            ah[tt] = *reinterpret_cast<const short8*>(&Ah[(wr * 64 + tt * 16 + lrow) * APAD + q * 8]);
            if (SPLITA)
                al[tt] = *reinterpret_cast<const short8*>(&Al[(wr * 64 + tt * 16 + lrow) * APAD + q * 8]);
        }
#pragma unroll
        for (int cc = 0; cc < 2; cc++) {
            int cb = wc * 2 + cc;
            short8 bh = *reinterpret_cast<const short8*>(&Bh[(cb * 16 + lrow) * APAD + q * 8]);
            short8 bl = *reinterpret_cast<const short8*>(&Bl[(cb * 16 + lrow) * APAD + q * 8]);
#pragma unroll
            for (int tt = 0; tt < 4; tt++) {
                acc[tt][cc] = __builtin_amdgcn_mfma_f32_16x16x32_bf16(ah[tt], bl, acc[tt][cc], 0, 0, 0);
                if (SPLITA)
                    acc[tt][cc] = __builtin_amdgcn_mfma_f32_16x16x32_bf16(al[tt], bh, acc[tt][cc], 0, 0, 0);
                acc[tt][cc] = __builtin_amdgcn_mfma_f32_16x16x32_bf16(ah[tt], bh, acc[tt][cc], 0, 0, 0);
            }
        }
        __syncthreads();
        if (t + 1 < NT) { write_t(); __syncthreads(); }
    }

#pragma unroll
    for (int t = 0; t < 4; t++) {
#pragma unroll
        for (int r = 0; r < 4; r++) {
            int gmo = m0 + wr * 64 + t * 16 + q * 4 + r;
            if (gmo >= M) continue;
#pragma unroll
            for (int cc = 0; cc < 2; cc++) {
                int gn = (wc * 2 + cc) * 16 + lrow;
                float v = acc[t][cc][r];
                if (BIAS) v += bias[gn];
                if (ACC)  v += C[(size_t)gmo * HF + gn];
                if (RELU) v = fmaxf(v, 0.f);
                C[(size_t)gmo * HF + gn] = v;
                if (BF16OUT) Cb[(size_t)gmo * HF + gn] = f2bf(v);
            }
        }
    }
}

// ================= merged RGCN layer GEMM: 128-tile, 512 threads, T14 pipelined =================
// hout = relu( aggb[N,1024] @ W[0:1024]^T + hin[N,128] @ root^T + bias ), + bf16 mirror.
__global__ __launch_bounds__(512) void gemm_rgcn(const unsigned short* __restrict__ aggb,
                                                 const float* __restrict__ hin,
                                                 const unsigned short* __restrict__ Bthi,
                                                 const unsigned short* __restrict__ Btlo,
                                                 float* __restrict__ hout,
                                                 unsigned short* __restrict__ hbout,
                                                 const float* __restrict__ bias, int M) {
    const int LDK = (RR + 1) * HF;  // 1152
    __shared__ unsigned short Ah[128 * APAD];
    __shared__ unsigned short Al[128 * APAD];
    __shared__ unsigned short Bh[128 * APAD];
    __shared__ unsigned short Bl[128 * APAD];
    const int tid  = threadIdx.x;
    const int m0   = blockIdx.x * 128;
    const int wr   = (tid >> 6) >> 2;     // 0..1
    const int wc   = (tid >> 6) & 3;      // 0..3
    const int lane = tid & 63;
    const int lrow = lane & 15;
    const int q    = lane >> 4;

    f32x4 acc[4][2];
#pragma unroll
    for (int t = 0; t < 4; t++)
#pragma unroll
        for (int c = 0; c < 2; c++) acc[t][c] = (f32x4){0.f, 0.f, 0.f, 0.f};

    const int srow  = tid >> 2;           // 0..127
    const int spart = (tid & 3) * 8;      // 0/8/16/24
    const int gm    = m0 + srow;

    // staged regs (phase 1: bf16 A; phase 2: fp32 A)
    uint4 rva1 = make_uint4(0u, 0u, 0u, 0u);
    float rva2[8];
    uint4 rvbh, rvbl;

    auto load1 = [&](int k0) {
        rva1 = make_uint4(0u, 0u, 0u, 0u);
        if (gm < M) rva1 = *reinterpret_cast<const uint4*>(&aggb[(size_t)gm * (RR * HF) + k0 + spart]);
        rvbh = *reinterpret_cast<const uint4*>(&Bthi[(size_t)srow * LDK + k0 + spart]);
        rvbl = *reinterpret_cast<const uint4*>(&Btlo[(size_t)srow * LDK + k0 + spart]);
    };
    auto write1 = [&]() {
        *reinterpret_cast<uint4*>(&Ah[srow * APAD + spart]) = rva1;
        *reinterpret_cast<uint4*>(&Bh[srow * APAD + spart]) = rvbh;
        *reinterpret_cast<uint4*>(&Bl[srow * APAD + spart]) = rvbl;
    };
    auto load2 = [&](int k0) {
        if (gm < M) {
            const float* ap = &hin[(size_t)gm * HF + k0 + spart];
            float4 v0 = *reinterpret_cast<const float4*>(ap);
            float4 v1 = *reinterpret_cast<const float4*>(ap + 4);
            rva2[0] = v0.x; rva2[1] = v0.y; rva2[2] = v0.z; rva2[3] = v0.w;
            rva2[4] = v1.x; rva2[5] = v1.y; rva2[6] = v1.z; rva2[7] = v1.w;
        } else {
#pragma unroll
            for (int j = 0; j < 8; j++) rva2[j] = 0.f;
        }
        rvbh = *reinterpret_cast<const uint4*>(&Bthi[(size_t)srow * LDK + RR * HF + k0 + spart]);
        rvbl = *reinterpret_cast<const uint4*>(&Btlo[(size_t)srow * LDK + RR * HF + k0 + spart]);
    };
    auto write2 = [&]() {
        unsigned hw[4], lw[4];
#pragma unroll
        for (int j = 0; j < 4; j++) {
            unsigned short h0 = f2bf(rva2[2 * j]);
            unsigned short h1 = f2bf(rva2[2 * j + 1]);
            unsigned short l0 = f2bf(rva2[2 * j] - bf2f(h0));
            unsigned short l1 = f2bf(rva2[2 * j + 1] - bf2f(h1));
            hw[j] = (unsigned)h0 | ((unsigned)h1 << 16);
            lw[j] = (unsigned)l0 | ((unsigned)l1 << 16);
        }
        *reinterpret_cast<uint4*>(&Ah[srow * APAD + spart]) = make_uint4(hw[0], hw[1], hw[2], hw[3]);
        *reinterpret_cast<uint4*>(&Al[srow * APAD + spart]) = make_uint4(lw[0], lw[1], lw[2], lw[3]);
        *reinterpret_cast<uint4*>(&Bh[srow * APAD + spart]) = rvbh;
        *reinterpret_cast<uint4*>(&Bl[srow * APAD + spart]) = rvbl;
    };

    // ---- phase 1: K = 0..1024, A = aggb (bf16), pipelined; prefetch phase-2 tile 0 at the tail ----
    load1(0); write1(); __syncthreads();
    for (int t = 0; t < 32; t++) {
        if (t < 31) load1((t + 1) * BK);
        else        load2(0);

        short8 ah[4];
#pragma unroll
        for (int tt = 0; tt < 4; tt++)
            ah[tt] = *reinterpret_cast<const short8*>(&Ah[(wr * 64 + tt * 16 + lrow) * APAD + q * 8]);
#pragma unroll
        for (int cc = 0; cc < 2; cc++) {
            int cb = wc * 2 + cc;
            short8 bh = *reinterpret_cast<const short8*>(&Bh[(cb * 16 + lrow) * APAD + q * 8]);
            short8 bl = *reinterpret_cast<const short8*>(&Bl[(cb * 16 + lrow) * APAD + q * 8]);
#pragma unroll
            for (int tt = 0; tt < 4; tt++) {
                acc[tt][cc] = __builtin_amdgcn_mfma_f32_16x16x32_bf16(ah[tt], bl, acc[tt][cc], 0, 0, 0);
                acc[tt][cc] = __builtin_amdgcn_mfma_f32_16x16x32_bf16(ah[tt], bh, acc[tt][cc], 0, 0, 0);
            }
        }
        __syncthreads();
        if (t < 31) write1(); else write2();
        __syncthreads();
    }

    // ---- phase 2: K = 1024..1152, A = hin (fp32 split), pipelined ----
    for (int t = 0; t < 4; t++) {
        if (t < 3) load2((t + 1) * BK);

        short8 ah[4], al[4];
#pragma unroll
        for (int tt = 0; tt < 4; tt++) {
            ah[tt] = *reinterpret_cast<const short8*>(&Ah[(wr * 64 + tt * 16 + lrow) * APAD + q * 8]);
            al[tt] = *reinterpret_cast<const short8*>(&Al[(wr * 64 + tt * 16 + lrow) * APAD + q * 8]);
        }
#pragma unroll
        for (int cc = 0; cc < 2; cc++) {
            int cb = wc * 2 + cc;
            short8 bh = *reinterpret_cast<const short8*>(&Bh[(cb * 16 + lrow) * APAD + q * 8]);
            short8 bl = *reinterpret_cast<const short8*>(&Bl[(cb * 16 + lrow) * APAD + q * 8]);
#pragma unroll
            for (int tt = 0; tt < 4; tt++) {
                acc[tt][cc] = __builtin_amdgcn_mfma_f32_16x16x32_bf16(ah[tt], bl, acc[tt][cc], 0, 0, 0);
                acc[tt][cc] = __builtin_amdgcn_mfma_f32_16x16x32_bf16(al[tt], bh, acc[tt][cc], 0, 0, 0);
                acc[tt][cc] = __builtin_amdgcn_mfma_f32_16x16x32_bf16(ah[tt], bh, acc[tt][cc], 0, 0, 0);
            }
        }
        if (t < 3) {
            __syncthreads();
            write2();
            __syncthreads();
        }
    }

#pragma unroll
    for (int t = 0; t < 4; t++) {
#pragma unroll
        for (int r = 0; r < 4; r++) {
            int gmo = m0 + wr * 64 + t * 16 + q * 4 + r;
            if (gmo >= M) continue;
#pragma unroll
            for (int cc = 0; cc < 2; cc++) {
                int gn = (wc * 2 + cc) * 16 + lrow;
                float v = fmaxf(acc[t][cc][r] + bias[gn], 0.f);
                hout[(size_t)gmo * HF + gn] = v;
                hbout[(size_t)gmo * HF + gn] = f2bf(v);
            }
        }
    }
}

// ================= z GEMM with fused attention scores =================
__global__ __launch_bounds__(256) void gemm_z(const float* __restrict__ hin,
                                              const unsigned short* __restrict__ Bthi,
                                              const unsigned short* __restrict__ Btlo,
                                              const float* __restrict__ att,
                                              unsigned short* __restrict__ zb,
                                              float* __restrict__ a_src,
                                              float* __restrict__ a_tgt, int M) {
    __shared__ unsigned short Ah[128 * APAD];
    __shared__ unsigned short Al[128 * APAD];
    __shared__ unsigned short Bh[128 * APAD];
    __shared__ unsigned short Bl[128 * APAD];
    const int tid  = threadIdx.x;
    const int m0   = blockIdx.x * 128;
    const int w    = tid >> 6;
    const int lane = tid & 63;
    const int lrow = lane & 15;
    const int q    = lane >> 4;

    f32x4 acc[2][8];
#pragma unroll
    for (int t = 0; t < 2; t++)
#pragma unroll
        for (int c = 0; c < 8; c++) acc[t][c] = (f32x4){0.f, 0.f, 0.f, 0.f};

    const int srow  = tid >> 1;
    const int spart = (tid & 1) * 16;

    for (int k0 = 0; k0 < HF; k0 += BK) {
        {
            int gm = m0 + srow;
            float va[16];
            if (gm < M) {
                const float* ap = &hin[(size_t)gm * HF + k0 + spart];
#pragma unroll
                for (int j = 0; j < 4; j++) {
                    float4 v = *reinterpret_cast<const float4*>(ap + j * 4);
                    va[j * 4 + 0] = v.x; va[j * 4 + 1] = v.y; va[j * 4 + 2] = v.z; va[j * 4 + 3] = v.w;
                }
            } else {
#pragma unroll
                for (int j = 0; j < 16; j++) va[j] = 0.f;
            }
            unsigned hw[8], lw[8];
#pragma unroll
            for (int j = 0; j < 8; j++) {
                unsigned short h0 = f2bf(va[2 * j]);
                unsigned short h1 = f2bf(va[2 * j + 1]);
                unsigned short l0 = f2bf(va[2 * j] - bf2f(h0));
                unsigned short l1 = f2bf(va[2 * j + 1] - bf2f(h1));
                hw[j] = (unsigned)h0 | ((unsigned)h1 << 16);
                lw[j] = (unsigned)l0 | ((unsigned)l1 << 16);
            }
            *reinterpret_cast<uint4*>(&Ah[srow * APAD + spart])     = make_uint4(hw[0], hw[1], hw[2], hw[3]);
            *reinterpret_cast<uint4*>(&Ah[srow * APAD + spart + 8]) = make_uint4(hw[4], hw[5], hw[6], hw[7]);
            *reinterpret_cast<uint4*>(&Al[srow * APAD + spart])     = make_uint4(lw[0], lw[1], lw[2], lw[3]);
            *reinterpret_cast<uint4*>(&Al[srow * APAD + spart + 8]) = make_uint4(lw[4], lw[5], lw[6], lw[7]);
        }
        {
            const unsigned short* bh = &Bthi[(size_t)srow * HF + k0 + spart];
            const unsigned short* bl = &Btlo[(size_t)srow * HF + k0 + spart];
            *reinterpret_cast<uint4*>(&Bh[srow * APAD + spart])     = *reinterpret_cast<const uint4*>(bh);
            *reinterpret_cast<uint4*>(&Bh[srow * APAD + spart + 8]) = *reinterpret_cast<const uint4*>(bh + 8);
            *reinterpret_cast<uint4*>(&Bl[srow * APAD + spart])     = *reinterpret_cast<const uint4*>(bl);
            *reinterpret_cast<uint4*>(&Bl[srow * APAD + spart + 8]) = *reinterpret_cast<const uint4*>(bl + 8);
        }
        __syncthreads();
        short8 ah[2], al[2];
#pragma unroll
        for (int t = 0; t < 2; t++) {
            ah[t] = *reinterpret_cast<const short8*>(&Ah[(w * 32 + t * 16 + lrow) * APAD + q * 8]);
            al[t] = *reinterpret_cast<const short8*>(&Al[(w * 32 + t * 16 + lrow) * APAD + q * 8]);
        }
#pragma unroll
        for (int c = 0; c < 8; c++) {
            short8 bh = *reinterpret_cast<const short8*>(&Bh[(c * 16 + lrow) * APAD + q * 8]);
            short8 bl = *reinterpret_cast<const short8*>(&Bl[(c * 16 + lrow) * APAD + q * 8]);
#pragma unroll
            for (int t = 0; t < 2; t++) {
                acc[t][c] = __builtin_amdgcn_mfma_f32_16x16x32_bf16(ah[t], bl, acc[t][c], 0, 0, 0);
                acc[t][c] = __builtin_amdgcn_mfma_f32_16x16x32_bf16(al[t], bh, acc[t][c], 0, 0, 0);
                acc[t][c] = __builtin_amdgcn_mfma_f32_16x16x32_bf16(ah[t], bh, acc[t][c], 0, 0, 0);
            }
        }
        __syncthreads();
    }

    float att_s[8], att_t[8];
#pragma unroll
    for (int c = 0; c < 8; c++) {
        att_s[c] = att[c * 32 + lrow];
        att_t[c] = att[c * 32 + 16 + lrow];
    }

#pragma unroll
    for (int t = 0; t < 2; t++) {
#pragma unroll
        for (int r = 0; r < 4; r++) {
            int gm = m0 + w * 32 + t * 16 + q * 4 + r;
            if (gm >= M) continue;
#pragma unroll
            for (int c = 0; c < 8; c++) {
                int gn = c * 16 + lrow;
                float v = acc[t][c][r];
                zb[(size_t)gm * HF + gn] = f2bf(v);
                float ps = v * att_s[c];
                float pt = v * att_t[c];
#pragma unroll
                for (int off = 1; off < 16; off <<= 1) {
                    ps += __shfl_xor(ps, off);
                    pt += __shfl_xor(pt, off);
                }
                if (lrow == 0) {
                    a_src[(size_t)gm * NHEADS + c] = ps;
                    a_tgt[(size_t)gm * NHEADS + c] = pt;
                }
            }
        }
    }
}

// ================= RGCN gather: all 8 relations concurrent per wave =================
__device__ inline void acc8(float* a, uint4 v) {
    a[0] += bf2f((unsigned short)(v.x & 0xffffu));
    a[1] += bf2f((unsigned short)(v.x >> 16));
    a[2] += bf2f((unsigned short)(v.y & 0xffffu));
    a[3] += bf2f((unsigned short)(v.y >> 16));
    a[4] += bf2f((unsigned short)(v.z & 0xffffu));
    a[5] += bf2f((unsigned short)(v.z >> 16));
    a[6] += bf2f((unsigned short)(v.w & 0xffffu));
    a[7] += bf2f((unsigned short)(v.w >> 16));
}

__global__ __launch_bounds__(256) void rgcn_agg_sorted(const unsigned short* __restrict__ hb,
                                                       const int* __restrict__ rowptr2,
                                                       const int* __restrict__ csr_src2,
                                                       unsigned short* __restrict__ agg) {
    int w = (blockIdx.x * 256 + threadIdx.x) >> 6;
    if (w >= NN) return;
    int lane = threadIdx.x & 63;
    int r    = lane >> 3;          // relation handled by this lane's group
    int cg   = (lane & 7) * 16;    // 16 columns (32 B) of the 128-wide row
    int b8   = w * RR;

    int rp  = rowptr2[b8 + (lane < 9 ? lane : 8)];
    int beg = __shfl(rp, r);
    int end = __shfl(rp, r + 1);

    float a[16];
#pragma unroll
    for (int j = 0; j < 16; j++) a[j] = 0.f;

    int e = beg;
    for (; e + 1 < end; e += 2) {
        int s0 = csr_src2[e];
        int s1 = csr_src2[e + 1];
        const uint4* p0 = reinterpret_cast<const uint4*>(&hb[(size_t)s0 * HF + cg]);
        const uint4* p1 = reinterpret_cast<const uint4*>(&hb[(size_t)s1 * HF + cg]);
        uint4 v00 = p0[0];
        uint4 v01 = p0[1];
        uint4 v10 = p1[0];
        uint4 v11 = p1[1];
        acc8(a,     v00);
        acc8(a + 8, v01);
        acc8(a,     v10);
        acc8(a + 8, v11);
    }
    if (e < end) {
        int s0 = csr_src2[e];
        const uint4* p0 = reinterpret_cast<const uint4*>(&hb[(size_t)s0 * HF + cg]);
        uint4 v00 = p0[0];
        uint4 v01 = p0[1];
        acc8(a,     v00);
        acc8(a + 8, v01);
    }

    int n = end - beg;
    float inv = 1.f / (float)(n > 1 ? n : 1);
    unsigned ow[8];
#pragma unroll
    for (int j = 0; j < 8; j++) {
        ow[j] = (unsigned)f2bf(a[2 * j] * inv) | ((unsigned)f2bf(a[2 * j + 1] * inv) << 16);
    }
    unsigned short* o = &agg[(size_t)w * (RR * HF) + r * HF + cg];
    *reinterpret_cast<uint4*>(o)     = make_uint4(ow[0], ow[1], ow[2], ow[3]);
    *reinterpret_cast<uint4*>(o + 8) = make_uint4(ow[4], ow[5], ow[6], ow[7]);
}

// ================= GAT: two-pass, chunked-shuffle weights + half-split accumulate =================
__global__ __launch_bounds__(256) void gat_kernel(const int* __restrict__ rowptr2,
                                                  const int* __restrict__ csr_src2,
                                                  const float* __restrict__ a_src,
                                                  const float* __restrict__ a_tgt,
                                                  const unsigned short* __restrict__ zb,
                                                  const float* __restrict__ bg,
                                                  const float* __restrict__ Wf,
                                                  const float* __restrict__ bf,
                                                  float* __restrict__ out) {
    int w = (blockIdx.x * 256 + threadIdx.x) >> 6;
    if (w >= NN) return;
    int lane = threadIdx.x & 63;
    int beg = rowptr2[w * RR], end = rowptr2[w * RR + RR];

    // ---- pass A: segment max, 8 edges x 8 heads in parallel ----
    int hdA = lane & 7;
    int e8  = lane >> 3;
    float atA = a_tgt[w * NHEADS + hdA];
    float m = -1e30f;
    for (int e = beg + e8; e < end; e += 8) {
        int s = csr_src2[e];
        float a = a_src[s * NHEADS + hdA] + atA;
        a = a > 0.f ? a : 0.2f * a;
        m = fmaxf(m, a);
    }
    m = fmaxf(m, __shfl_xor(m, 8));
    m = fmaxf(m, __shfl_xor(m, 16));
    m = fmaxf(m, __shfl_xor(m, 32));

    // ---- pass B: chunked weights + half-split accumulate ----
    int half = lane >> 5;
    int l32  = lane & 31;
    int hd   = l32 >> 2;
    int c0   = l32 * 4;

    float l = 0.f;
    float ax0 = 0.f, ax1 = 0.f, ax2 = 0.f, ax3 = 0.f;

    for (int e0 = beg; e0 < end; e0 += 8) {
        int eA = e0 + e8;
        float wA = 0.f;
        int   sA = 0;
        if (eA < end) {
            sA = csr_src2[eA];
            float a = a_src[sA * NHEADS + hdA] + atA;
            a = a > 0.f ? a : 0.2f * a;
            wA = __expf(a - m);
        }
#pragma unroll
        for (int j = 0; j < 4; j++) {
            int idx  = (2 * j + half) * 8 + hd;
            float wv = __shfl(wA, idx);
            int   sv = __shfl(sA, idx);
            uint2 z = *reinterpret_cast<const uint2*>(&zb[(size_t)sv * HF + c0]);
            l   += wv;
            ax0 += bf2f((unsigned short)(z.x & 0xffffu)) * wv;
            ax1 += bf2f((unsigned short)(z.x >> 16)) * wv;
            ax2 += bf2f((unsigned short)(z.y & 0xffffu)) * wv;
            ax3 += bf2f((unsigned short)(z.y >> 16)) * wv;
        }
    }
    l   += __shfl_xor(l, 32);
    ax0 += __shfl_xor(ax0, 32);
    ax1 += __shfl_xor(ax1, 32);
    ax2 += __shfl_xor(ax2, 32);
    ax3 += __shfl_xor(ax3, 32);

    float inv = 1.f / fmaxf(l, 1e-16f);
    float v0 = ax0 * inv + bg[c0];
    float v1 = ax1 * inv + bg[c0 + 1];
    float v2 = ax2 * inv + bg[c0 + 2];
    float v3 = ax3 * inv + bg[c0 + 3];

    float p0 = v0 * Wf[c0 * 3 + 0] + v1 * Wf[(c0 + 1) * 3 + 0]
             + v2 * Wf[(c0 + 2) * 3 + 0] + v3 * Wf[(c0 + 3) * 3 + 0];
    float p1 = v0 * Wf[c0 * 3 + 1] + v1 * Wf[(c0 + 1) * 3 + 1]
             + v2 * Wf[(c0 + 2) * 3 + 1] + v3 * Wf[(c0 + 3) * 3 + 1];
    float p2 = v0 * Wf[c0 * 3 + 2] + v1 * Wf[(c0 + 1) * 3 + 2]
             + v2 * Wf[(c0 + 2) * 3 + 2] + v3 * Wf[(c0 + 3) * 3 + 2];
#pragma unroll
    for (int off = 16; off > 0; off >>= 1) {
        p0 += __shfl_xor(p0, off);
        p1 += __shfl_xor(p1, off);
        p2 += __shfl_xor(p2, off);
    }
    if (lane == 0) {
        float l0v = p0 + bf[0], l1v = p1 + bf[1], l2v = p2 + bf[2];
        float mm = fmaxf(l0v, fmaxf(l1v, l2v));
        float lse = mm + logf(expf(l0v - mm) + expf(l1v - mm) + expf(l2v - mm));
        out[(size_t)w * 3 + 0] = l0v - lse;
        out[(size_t)w * 3 + 1] = l1v - lse;
        out[(size_t)w * 3 + 2] = l2v - lse;
    }
}

// ================= launch =================
extern "C" void kernel_launch(void* const* d_in, const int* in_sizes, int n_in,
                              void* d_out, int out_size, void* d_ws, size_t ws_size,
                              hipStream_t stream) {
    const float* x     = (const float*)d_in[0];
    const int*   ei    = (const int*)d_in[1];
    const int*   etype = (const int*)d_in[2];
    const float* Wp    = (const float*)d_in[3];
    const float* bp    = (const float*)d_in[4];
    const float* W1    = (const float*)d_in[5];
    const float* root1 = (const float*)d_in[6];
    const float* b1    = (const float*)d_in[7];
    const float* W2    = (const float*)d_in[8];
    const float* root2 = (const float*)d_in[9];
    const float* b2    = (const float*)d_in[10];
    const float* Wg    = (const float*)d_in[11];
    const float* att   = (const float*)d_in[12];
    const float* bg    = (const float*)d_in[13];
    const float* Wf    = (const float*)d_in[14];
    const float* bf    = (const float*)d_in[15];
    (void)in_sizes; (void)n_in; (void)out_size; (void)ws_size;

    const int* srcv = ei;
    const int* tgtv = ei + EE;

    // ---- workspace layout (bytes), ~185.4 MB ----
    char* base = (char*)d_ws;
    unsigned short* aggb = (unsigned short*)(base + 0);   // N*1024*2 = 102,400,000
    int* cnt2    = (int*)(base + 96000000);               // 1,600,000 (aliased, dead before walk 1)
    int* cursor2 = (int*)(base + 98000000);               // 1,600,000
    int* bsum2   = (int*)(base + 99700000);               // 6,256
    int* bbase2  = (int*)(base + 99800000);               // 6,256
    unsigned short* zb = (unsigned short*)(base + 0);     // 12,800,000 (GAT phase)
    float* a_src = (float*)(base + 12800000);             // 1,600,000
    float* a_tgt = (float*)(base + 14400000);             // 1,600,000
    float* h1    = (float*)(base + 102400000);            // 25,600,000
    float* h2    = (float*)(base + 128000000);            // 25,600,000
    unsigned short* h1b = (unsigned short*)(base + 153600000); // 12,800,000
    unsigned short* h2b = (unsigned short*)(base + 166400000); // 12,800,000
    int* csr_src2 = (int*)(base + 179200000);             // 3,200,000
    int* rowptr2  = (int*)(base + 182400000);             // 1,600,016
    unsigned short* Wtp_hi = (unsigned short*)(base + 184000016); // 65,536
    unsigned short* Wtp_lo = (unsigned short*)(base + 184065552); // 65,536
    unsigned short* Wt1_hi = (unsigned short*)(base + 184131088); // 294,912
    unsigned short* Wt1_lo = (unsigned short*)(base + 184426000); // 294,912
    unsigned short* Wt2_hi = (unsigned short*)(base + 184720912); // 294,912
    unsigned short* Wt2_lo = (unsigned short*)(base + 185015824); // 294,912
    unsigned short* Wtg_hi = (unsigned short*)(base + 185310736); // 32,768
    unsigned short* Wtg_lo = (unsigned short*)(base + 185343504); // 32,768

    // ---- weight prep: one dispatch ----
    prep_weights<<<cdiv(344064, 256), 256, 0, stream>>>(
        Wp, W1, root1, W2, root2, Wg,
        Wtp_hi, Wtp_lo, Wt1_hi, Wt1_lo, Wt2_hi, Wt2_lo, Wtg_hi, Wtg_lo);

    // ---- CSR build, sorted by (tgt, rel) ----
    hipMemsetAsync(cnt2, 0, (size_t)M2 * 4, stream);
    count2_kernel<<<cdiv(EE, 256), 256, 0, stream>>>(tgtv, etype, cnt2);
    scan1_kernel<<<NB2, 256, 0, stream>>>(cnt2, bsum2, M2);
    scan2_kernel<<<1, 256, 0, stream>>>(bsum2, bbase2, &rowptr2[M2], NB2, CH2);
    scan3_kernel<<<NB2, 256, 0, stream>>>(cnt2, bbase2, rowptr2, cursor2, M2);
    fill2_kernel<<<cdiv(EE, 256), 256, 0, stream>>>(srcv, tgtv, etype, cursor2, csr_src2);

    const int ggrid  = cdiv(NN, 128);   // 391
    const int nwgrid = cdiv(NN, 4);

    // ---- projection: h1 = x @ Wp + bp (fp32-effective) + h1b mirror ----
    gemm_mfma<true, false, true, false, true><<<ggrid, 512, 0, stream>>>(
        x, DIN, Wtp_hi, Wtp_lo, DIN, h1, h1b, bp, NN, DIN);

    // ---- RGCN layer 1: h1 -> h2 ----
    rgcn_agg_sorted<<<nwgrid, 256, 0, stream>>>(h1b, rowptr2, csr_src2, aggb);
    gemm_rgcn<<<ggrid, 512, 0, stream>>>(aggb, h1, Wt1_hi, Wt1_lo, h2, h2b, b1, NN);

    // ---- RGCN layer 2: h2 -> h1 ----
    rgcn_agg_sorted<<<nwgrid, 256, 0, stream>>>(h2b, rowptr2, csr_src2, aggb);
    gemm_rgcn<<<ggrid, 512, 0, stream>>>(aggb, h2, Wt2_hi, Wt2_lo, h1, h1b, b2, NN);

    // ---- GAT: z GEMM (fused scores) + two-pass softmax-aggregate ----
    gemm_z<<<ggrid, 256, 0, stream>>>(h1, Wtg_hi, Wtg_lo, att, zb, a_src, a_tgt, NN);
    gat_kernel<<<nwgrid, 256, 0, stream>>>(rowptr2, csr_src2, a_src, a_tgt, zb, bg, Wf, bf, (float*)d_out);
}